// Round 3
// baseline (172.272 us; speedup 1.0000x reference)
//
#include <hip/hip_runtime.h>

#define BATCH 512
#define NPART 60
#define PFEAT 20
#define SFEAT 14
#define NVTX  5
#define HID   60
#define DE    20
#define DO    24
#define NCLS  2
#define SR    68          // LDS row stride in halves: 34 words -> 2-way banks max

typedef _Float16 half8  __attribute__((ext_vector_type(8)));
typedef _Float16 half4v __attribute__((ext_vector_type(4)));
typedef __fp16   fp16x2 __attribute__((ext_vector_type(2)));
typedef float    f32x4  __attribute__((ext_vector_type(4)));

__device__ __forceinline__ half4v pkcvt4(f32x4 a) {
    fp16x2 lo = __builtin_amdgcn_cvt_pkrtz(a[0], a[1]);
    fp16x2 hi = __builtin_amdgcn_cvt_pkrtz(a[2], a[3]);
    half4v r;
    r[0] = (_Float16)lo[0]; r[1] = (_Float16)lo[1];
    r[2] = (_Float16)hi[0]; r[3] = (_Float16)hi[1];
    return r;
}
__device__ __forceinline__ half4v relu4(half4v a) {
#pragma unroll
    for (int j = 0; j < 4; ++j)
        a[j] = (a[j] > (_Float16)0.f) ? a[j] : (_Float16)0.f;
    return a;
}
__device__ __forceinline__ f32x4 bias4(const float* b, int col4, int lim) {
    f32x4 z = {0.f, 0.f, 0.f, 0.f};
    return (col4 < lim) ? *(const f32x4*)(b + col4) : z;
}

// ---------------------------------------------------------------------------
// Pack kernel — 16 blocks, one element/thread (round-11, proven).
// ---------------------------------------------------------------------------
__global__ __launch_bounds__(256) void pack_kernel(
    const float* __restrict__ fr_w2, const float* __restrict__ fr_w3,
    const float* __restrict__ pv_w2, const float* __restrict__ pv_w3,
    const float* __restrict__ fo_w1, const float* __restrict__ fo_w2,
    const float* __restrict__ fo_w3,
    _Float16* __restrict__ frW2p, _Float16* __restrict__ frW3p16,
    _Float16* __restrict__ pvW2p, _Float16* __restrict__ pvW3p16,
    _Float16* __restrict__ foW1p, _Float16* __restrict__ foW2p16,
    _Float16* __restrict__ foW3p16)
{
    int idx = blockIdx.x*256 + threadIdx.x;    // 0..4095
    {   // x32 tables, u<4, kk<2
        int j  = idx & 7;
        int L  = (idx >> 3) & 63;
        int kk = (idx >> 9) & 1;
        int u  = idx >> 10;
        int k  = kk*32 + (L >> 4)*8 + j;
        int n  = u*16 + (L & 15);
        bool ok = (k < HID && n < HID);
        frW2p[idx] = (_Float16)(ok ? fr_w2[k*HID + n] : 0.f);
        pvW2p[idx] = (_Float16)(ok ? pv_w2[k*HID + n] : 0.f);
        foW1p[idx] = (_Float16)(ok ? fo_w1[k*HID + n] : 0.f);
    }
    {   // x16 table, u<4: fo_w2
        int j  = idx & 3;
        int L  = (idx >> 2) & 63;
        int kt = (idx >> 8) & 3;
        int u  = idx >> 10;
        int k  = kt*16 + (L >> 4)*4 + j;
        int n  = u*16 + (L & 15);
        foW2p16[idx] = (_Float16)((k < HID && n < HID) ? fo_w2[k*HID + n] : 0.f);
    }
    if (idx < 2048) {   // x16 tables, u<2: w3
        int j  = idx & 3;
        int L  = (idx >> 2) & 63;
        int kt = (idx >> 8) & 3;
        int u  = idx >> 10;
        int k  = kt*16 + (L >> 4)*4 + j;
        int n  = u*16 + (L & 15);
        frW3p16[idx] = (_Float16)((k < HID && n < DE) ? fr_w3[k*DE + n] : 0.f);
        pvW3p16[idx] = (_Float16)((k < HID && n < DE) ? pv_w3[k*DE + n] : 0.f);
        foW3p16[idx] = (_Float16)((k < HID && n < DO) ? fo_w3[k*DO + n] : 0.f);
    }
}

// ---------------------------------------------------------------------------
// Fused network kernel v6: latency-bound diagnosis (all pipes <=35% busy,
// ~65% no-issue cycles, 4 waves/SIMD can't cover serial chains; r1's extra
// TLP didn't help; r2's source hoist was sunk by the compiler).
// Fix = ILP: P1a processes TWO receivers (rA,rB) per iteration as
// independent dependency chains sharing weight fragments, with overlapped
// butterflies. Packed fr/pv w2/w3 tables staged into LDS once per block
// (compiler can't sink that), taking weight reloads off the VMEM-latency
// path. VGPR must stay <=128 (2 blocks/CU = 4 waves/SIMD).
// ---------------------------------------------------------------------------
__global__ __launch_bounds__(512) void fused_kernel(
    const float* __restrict__ x, const float* __restrict__ y,
    const float* __restrict__ fr_w1, const float* __restrict__ fr_b1,
    const float* __restrict__ fr_b2, const float* __restrict__ fr_b3,
    const float* __restrict__ pv_w1, const float* __restrict__ pv_b1,
    const float* __restrict__ pv_b2, const float* __restrict__ pv_b3,
    const float* __restrict__ fo_b1, const float* __restrict__ fo_b2,
    const float* __restrict__ fo_b3,
    const float* __restrict__ fcw, const float* __restrict__ fcb,
    const half8*  __restrict__ frw2p, const half4v* __restrict__ frw3p16,
    const half8*  __restrict__ pvw2p, const half4v* __restrict__ pvw3p16,
    const half8*  __restrict__ fow1p, const half4v* __restrict__ fow2p16,
    const half4v* __restrict__ fow3p16,
    float* __restrict__ out)
{
    __shared__ __align__(16) _Float16 sFrA[NPART*SR];     // P2+: aliased as sCin
    __shared__ __align__(16) _Float16 sFrB[NPART*SR];
    __shared__ __align__(16) _Float16 sPvA[NPART*SR];
    __shared__ __align__(16) _Float16 sPvV[NVTX*64];
    __shared__ __align__(16) _Float16 sEpp[NPART*DE];
    __shared__ __align__(16) _Float16 sEpvP[NVTX*NPART*DE];
    __shared__ __align__(16) float    sDsum[4][DO];
    // packed weight tables in LDS (staged once per block in P0)
    __shared__ __align__(16) _Float16 sFrW2[4096];
    __shared__ __align__(16) _Float16 sFrW3[2048];
    __shared__ __align__(16) _Float16 sPvW2[4096];
    __shared__ __align__(16) _Float16 sPvW3[2048];
    _Float16* sCin = sFrA;

    int bb   = blockIdx.x;
    int wv   = threadIdx.x >> 6;     // 0..7
    int lane = threadIdx.x & 63;
    int ml   = lane & 15;
    int q    = lane >> 4;

    // ================= P0: stage A + weight tables ==========================
    {
        // cooperative copy of packed w2/w3 tables into LDS (1536 x 16B)
        for (int t = threadIdx.x; t < 1536; t += 512) {
            half8 v; _Float16* dst;
            if (t < 512)       { v = frw2p[t];                       dst = sFrW2 + t*8; }
            else if (t < 768)  { v = ((const half8*)frw3p16)[t-512]; dst = sFrW3 + (t-512)*8; }
            else if (t < 1280) { v = pvw2p[t-768];                   dst = sPvW2 + (t-768)*8; }
            else               { v = ((const half8*)pvw3p16)[t-1280];dst = sPvW3 + (t-1280)*8; }
            *(half8*)dst = v;
        }

        int tile = wv & 3;
        int row  = 16*tile + ml;
        int rr   = (row < NPART) ? row : 0;
        const float* xb = x + (size_t)bb*PFEAT*NPART;
        half8 bX;
#pragma unroll
        for (int j = 0; j < 8; ++j) {
            int k = q*8 + j;
            bX[j] = (_Float16)((k < PFEAT) ? xb[(size_t)k*NPART + rr] : 0.f);
        }
#pragma unroll
        for (int task = 0; task < 2; ++task) {
            const float* W; const float* bset; _Float16* Ot;
            if (wv < 4) {
                if (task == 0) { W = fr_w1;  bset = fr_b1;  Ot = sFrA; }
                else           { W = pv_w1;  bset = nullptr; Ot = sPvA; }
            } else {
                if (task == 1) break;
                W = fr_w1 + PFEAT*HID; bset = nullptr; Ot = sFrB;
            }
#pragma unroll
            for (int u = 0; u < 4; ++u) {
                int n = u*16 + ml;
                half8 w8;
#pragma unroll
                for (int j = 0; j < 8; ++j) {
                    int k = q*8 + j;
                    w8[j] = (_Float16)((k < PFEAT && n < HID) ? W[k*HID + n] : 0.f);
                }
                f32x4 acc = bset ? bias4(bset, u*16 + 4*q, HID - 3)
                                 : (f32x4){0.f, 0.f, 0.f, 0.f};
                acc = __builtin_amdgcn_mfma_f32_16x16x32_f16(w8, bX, acc, 0, 0, 0);
                if (row < NPART)
                    *(half4v*)(Ot + row*SR + u*16 + 4*q) = pkcvt4(acc);
            }
        }
        // pvV: 320 outputs, one per thread
        for (int idx = threadIdx.x; idx < NVTX*64; idx += 512) {
            int v = idx >> 6;
            int h = idx & 63;
            float a = 0.f;
            if (h < HID) {
                a = pv_b1[h];
#pragma unroll
                for (int f = 0; f < SFEAT; ++f)
                    a += y[((size_t)bb*SFEAT + f)*NVTX + v] * pv_w1[(PFEAT + f)*HID + h];
            }
            sPvV[idx] = (_Float16)a;
        }
    }
    __syncthreads();

    // ================= P1a: fr-edge, receiver PAIRS rA=wv+16j, rB=rA+8 ======
    {
        for (int j = 0; j < 4; ++j) {
            int rA = wv + 16*j;
            int rB = rA + 8;
            bool hasB = (rB < NPART);
            int rBs = hasB ? rB : rA;
            half8 uA[2], uB[2];
#pragma unroll
            for (int kk = 0; kk < 2; ++kk) {
                uA[kk] = *(const half8*)(sFrA + rA*SR  + kk*32 + q*8);
                uB[kk] = *(const half8*)(sFrA + rBs*SR + kk*32 + q*8);
            }
            float sA[2][4], sB[2][4];
#pragma unroll
            for (int v = 0; v < 2; ++v)
#pragma unroll
                for (int i = 0; i < 4; ++i) { sA[v][i] = 0.f; sB[v][i] = 0.f; }

#pragma unroll
            for (int c = 0; c < 4; ++c) {           // 16-edge chunk
                int edge = 16*c + ml;
                bool eok = (edge < NPART-1);
                int srA = eok ? (edge + (edge >= rA)) : 0;
                int srB = eok ? (edge + (edge >= rB)) : 0;
                half8 bAa[2], bAb[2];
#pragma unroll
                for (int kk = 0; kk < 2; ++kk) {
                    half8 va = *(const half8*)(sFrB + srA*SR + kk*32 + q*8);
                    half8 vb = *(const half8*)(sFrB + srB*SR + kk*32 + q*8);
                    half8 sa = uA[kk] + va;
                    half8 sb = uB[kk] + vb;
#pragma unroll
                    for (int jj = 0; jj < 8; ++jj) {
                        sa[jj] = (sa[jj] > (_Float16)0.f) ? sa[jj] : (_Float16)0.f;
                        sb[jj] = (sb[jj] > (_Float16)0.f) ? sb[jj] : (_Float16)0.f;
                    }
                    bAa[kk] = sa; bAb[kk] = sb;
                }
                f32x4 acc3a[2], acc3b[2];
#pragma unroll
                for (int v = 0; v < 2; ++v) {
                    f32x4 bi = bias4(fr_b3, v*16 + 4*q, DE - 3);
                    acc3a[v] = bi; acc3b[v] = bi;
                }
#pragma unroll
                for (int u = 0; u < 4; ++u) {
                    half8 w0 = *(const half8*)(sFrW2 + ((u*2+0)*64 + lane)*8);
                    half8 w1 = *(const half8*)(sFrW2 + ((u*2+1)*64 + lane)*8);
                    f32x4 bi2 = bias4(fr_b2, u*16 + 4*q, HID - 3);
                    f32x4 aA = bi2, aB = bi2;
                    aA = __builtin_amdgcn_mfma_f32_16x16x32_f16(w0, bAa[0], aA, 0, 0, 0);
                    aA = __builtin_amdgcn_mfma_f32_16x16x32_f16(w1, bAa[1], aA, 0, 0, 0);
                    aB = __builtin_amdgcn_mfma_f32_16x16x32_f16(w0, bAb[0], aB, 0, 0, 0);
                    aB = __builtin_amdgcn_mfma_f32_16x16x32_f16(w1, bAb[1], aB, 0, 0, 0);
                    half4v a3a = relu4(pkcvt4(aA));
                    half4v a3b = relu4(pkcvt4(aB));
                    half4v w3a = *(const half4v*)(sFrW3 + ((0*4+u)*64 + lane)*4);
                    half4v w3b = *(const half4v*)(sFrW3 + ((1*4+u)*64 + lane)*4);
                    acc3a[0] = __builtin_amdgcn_mfma_f32_16x16x16f16(w3a, a3a, acc3a[0], 0, 0, 0);
                    acc3a[1] = __builtin_amdgcn_mfma_f32_16x16x16f16(w3b, a3a, acc3a[1], 0, 0, 0);
                    acc3b[0] = __builtin_amdgcn_mfma_f32_16x16x16f16(w3a, a3b, acc3b[0], 0, 0, 0);
                    acc3b[1] = __builtin_amdgcn_mfma_f32_16x16x16f16(w3b, a3b, acc3b[1], 0, 0, 0);
                }
#pragma unroll
                for (int v = 0; v < 2; ++v)
#pragma unroll
                    for (int i = 0; i < 4; ++i) {
                        sA[v][i] += eok ? fmaxf(acc3a[v][i], 0.f) : 0.f;
                        sB[v][i] += eok ? fmaxf(acc3b[v][i], 0.f) : 0.f;
                    }
            }
            // two overlapped butterflies -> sEpp[rA], sEpp[rB]
#pragma unroll
            for (int v = 0; v < 2; ++v) {
#pragma unroll
                for (int i = 0; i < 4; ++i) {
                    sA[v][i] += __shfl_xor(sA[v][i], 1);
                    sB[v][i] += __shfl_xor(sB[v][i], 1);
                    sA[v][i] += __shfl_xor(sA[v][i], 2);
                    sB[v][i] += __shfl_xor(sB[v][i], 2);
                    sA[v][i] += __shfl_xor(sA[v][i], 4);
                    sB[v][i] += __shfl_xor(sB[v][i], 4);
                    sA[v][i] += __shfl_xor(sA[v][i], 8);
                    sB[v][i] += __shfl_xor(sB[v][i], 8);
                }
                int col4 = v*16 + 4*q;
                if (ml == 0 && col4 < DE) {
                    f32x4 oa = {sA[v][0], sA[v][1], sA[v][2], sA[v][3]};
                    *(half4v*)(sEpp + rA*DE + col4) = pkcvt4(oa);
                    if (hasB) {
                        f32x4 ob = {sB[v][0], sB[v][1], sB[v][2], sB[v][3]};
                        *(half4v*)(sEpp + rB*DE + col4) = pkcvt4(ob);
                    }
                }
            }
        }
    }

    // ================= P1b: pv groups, gv = wv (waves 0-4), t-pair halves ===
    if (wv < NVTX) {
        int gv = wv;
#pragma unroll
        for (int th = 0; th < 2; ++th) {
            half8 bA[2][2];
#pragma unroll
            for (int tl = 0; tl < 2; ++tl) {
                int p = 16*(2*th + tl) + ml;
                int sr = (p < NPART) ? p : 0;
#pragma unroll
                for (int kk = 0; kk < 2; ++kk) {
                    half8 u8 = *(const half8*)(sPvV + gv*64 + kk*32 + q*8);
                    half8 v8 = *(const half8*)(sPvA + sr*SR + kk*32 + q*8);
                    half8 s8 = u8 + v8;
#pragma unroll
                    for (int jj = 0; jj < 8; ++jj) {
                        _Float16 vj = s8[jj];
                        s8[jj] = (vj > (_Float16)0.f) ? vj : (_Float16)0.f;
                    }
                    bA[tl][kk] = s8;
                }
            }
            f32x4 acc3[2][2];
#pragma unroll
            for (int v = 0; v < 2; ++v) {
                f32x4 bi = bias4(pv_b3, v*16 + 4*q, DE - 3);
#pragma unroll
                for (int tl = 0; tl < 2; ++tl) acc3[v][tl] = bi;
            }
#pragma unroll
            for (int u = 0; u < 4; ++u) {
                half8 w0 = *(const half8*)(sPvW2 + ((u*2+0)*64 + lane)*8);
                half8 w1 = *(const half8*)(sPvW2 + ((u*2+1)*64 + lane)*8);
                f32x4 bi2 = bias4(pv_b2, u*16 + 4*q, HID - 3);
                half4v a3u[2];
#pragma unroll
                for (int tl = 0; tl < 2; ++tl) {
                    f32x4 a = bi2;
                    a = __builtin_amdgcn_mfma_f32_16x16x32_f16(w0, bA[tl][0], a, 0, 0, 0);
                    a = __builtin_amdgcn_mfma_f32_16x16x32_f16(w1, bA[tl][1], a, 0, 0, 0);
                    a3u[tl] = relu4(pkcvt4(a));
                }
                half4v w3a = *(const half4v*)(sPvW3 + ((0*4+u)*64 + lane)*4);
                half4v w3b = *(const half4v*)(sPvW3 + ((1*4+u)*64 + lane)*4);
#pragma unroll
                for (int tl = 0; tl < 2; ++tl) {
                    acc3[0][tl] = __builtin_amdgcn_mfma_f32_16x16x16f16(w3a, a3u[tl], acc3[0][tl], 0, 0, 0);
                    acc3[1][tl] = __builtin_amdgcn_mfma_f32_16x16x16f16(w3b, a3u[tl], acc3[1][tl], 0, 0, 0);
                }
            }
#pragma unroll
            for (int v = 0; v < 2; ++v) {
                int col4 = v*16 + 4*q;
#pragma unroll
                for (int tl = 0; tl < 2; ++tl) {
                    int p = 16*(2*th + tl) + ml;
                    if (p < NPART && col4 < DE) {
                        half4v hv = relu4(pkcvt4(acc3[v][tl]));
                        *(half4v*)(sEpvP + (gv*NPART + p)*DE + col4) = hv;
                    }
                }
            }
        }
    }
    __syncthreads();

    // ================= P2: cin gather into sCin (aliases sFrA) ==============
    for (int idx = threadIdx.x; idx < NPART*64; idx += 512) {
        int p = idx >> 6;
        int k = idx & 63;
        _Float16 v;
        if (k < PFEAT) {
            v = (_Float16)x[((size_t)bb*PFEAT + k)*NPART + p];
        } else if (k < PFEAT + DE) {
            v = sEpp[p*DE + (k - PFEAT)];
        } else if (k < PFEAT + 2*DE) {
            int c = k - PFEAT - DE;
            float s = 0.f;
#pragma unroll
            for (int g5 = 0; g5 < NVTX; ++g5)
                s += (float)sEpvP[(g5*NPART + p)*DE + c];
            v = (_Float16)s;
        } else {
            v = (_Float16)0.f;
        }
        sCin[p*SR + k] = v;
    }
    __syncthreads();

    // ================= P3: object MLP (waves 0-3, tile = wv) ================
    if (wv < 4) {
        int p = 16*wv + ml;
        int sp = (p < NPART) ? p : 0;
        half8 bC[2];
#pragma unroll
        for (int kk = 0; kk < 2; ++kk)
            bC[kk] = *(const half8*)(sCin + sp*SR + kk*32 + q*8);

        f32x4 acc1[4];
#pragma unroll
        for (int u = 0; u < 4; ++u) {
            acc1[u] = bias4(fo_b1, u*16 + 4*q, HID - 3);
            acc1[u] = __builtin_amdgcn_mfma_f32_16x16x32_f16(fow1p[(u*2 + 0)*64 + lane], bC[0], acc1[u], 0, 0, 0);
            acc1[u] = __builtin_amdgcn_mfma_f32_16x16x32_f16(fow1p[(u*2 + 1)*64 + lane], bC[1], acc1[u], 0, 0, 0);
        }
        half4v a2[4];
#pragma unroll
        for (int u = 0; u < 4; ++u) a2[u] = relu4(pkcvt4(acc1[u]));

        f32x4 acc2[4];
#pragma unroll
        for (int u = 0; u < 4; ++u) {
            acc2[u] = bias4(fo_b2, u*16 + 4*q, HID - 3);
#pragma unroll
            for (int kt = 0; kt < 4; ++kt)
                acc2[u] = __builtin_amdgcn_mfma_f32_16x16x16f16(fow2p16[(u*4 + kt)*64 + lane], a2[kt], acc2[u], 0, 0, 0);
        }
        half4v a3[4];
#pragma unroll
        for (int u = 0; u < 4; ++u) a3[u] = relu4(pkcvt4(acc2[u]));

        f32x4 acc3[2];
#pragma unroll
        for (int v = 0; v < 2; ++v) {
            acc3[v] = bias4(fo_b3, v*16 + 4*q, DO - 3);
#pragma unroll
            for (int u = 0; u < 4; ++u)
                acc3[v] = __builtin_amdgcn_mfma_f32_16x16x16f16(fow3p16[(v*4 + u)*64 + lane], a3[u], acc3[v], 0, 0, 0);
        }
#pragma unroll
        for (int v = 0; v < 2; ++v) {
            float s[4];
            bool ok = p < NPART;
#pragma unroll
            for (int i = 0; i < 4; ++i)
                s[i] = ok ? fmaxf(acc3[v][i], 0.f) : 0.f;
#pragma unroll
            for (int i = 0; i < 4; ++i) {
                s[i] += __shfl_xor(s[i], 1);
                s[i] += __shfl_xor(s[i], 2);
                s[i] += __shfl_xor(s[i], 4);
                s[i] += __shfl_xor(s[i], 8);
            }
            int col4 = v*16 + 4*q;
            if (ml == 0 && col4 < DO) {
                f32x4 o = {s[0], s[1], s[2], s[3]};
                *(f32x4*)(sDsum[wv] + col4) = o;
            }
        }
    }
    __syncthreads();

    // ================= fc head (wave 0) =====================================
    if (wv == 0) {
        float tot = 0.f;
        if (lane < DO) {
#pragma unroll
            for (int w4 = 0; w4 < 4; ++w4) tot += sDsum[w4][lane];
        }
        float p0 = (lane < DO) ? tot * fcw[lane*NCLS + 0] : 0.f;
        float p1 = (lane < DO) ? tot * fcw[lane*NCLS + 1] : 0.f;
#pragma unroll
        for (int d = 1; d <= 16; d <<= 1) {
            p0 += __shfl_xor(p0, d);
            p1 += __shfl_xor(p1, d);
        }
        if (lane == 0) {
            out[bb*NCLS + 0] = p0 + fcb[0];
            out[bb*NCLS + 1] = p1 + fcb[1];
        }
    }
}

// ---------------------------------------------------------------------------
extern "C" void kernel_launch(void* const* d_in, const int* in_sizes, int n_in,
                              void* d_out, int out_size, void* d_ws, size_t ws_size,
                              hipStream_t stream)
{
    const float* x     = (const float*)d_in[0];
    const float* y     = (const float*)d_in[1];
    const float* fr_w1 = (const float*)d_in[2];
    const float* fr_b1 = (const float*)d_in[3];
    const float* fr_w2 = (const float*)d_in[4];
    const float* fr_b2 = (const float*)d_in[5];
    const float* fr_w3 = (const float*)d_in[6];
    const float* fr_b3 = (const float*)d_in[7];
    const float* pv_w1 = (const float*)d_in[8];
    const float* pv_b1 = (const float*)d_in[9];
    const float* pv_w2 = (const float*)d_in[10];
    const float* pv_b2 = (const float*)d_in[11];
    const float* pv_w3 = (const float*)d_in[12];
    const float* pv_b3 = (const float*)d_in[13];
    const float* fo_w1 = (const float*)d_in[14];
    const float* fo_b1 = (const float*)d_in[15];
    const float* fo_w2 = (const float*)d_in[16];
    const float* fo_b2 = (const float*)d_in[17];
    const float* fo_w3 = (const float*)d_in[18];
    const float* fo_b3 = (const float*)d_in[19];
    const float* fc_w  = (const float*)d_in[20];
    const float* fc_b  = (const float*)d_in[21];
    float* out = (float*)d_out;

    char* wsb = (char*)d_ws;
    size_t off = 0;
    auto alloc = [&](size_t bytes) { char* p = wsb + off; off += (bytes + 255) & ~(size_t)255; return p; };

    _Float16* frW2p   = (_Float16*)alloc(4096*2);
    _Float16* frW3p16 = (_Float16*)alloc(2048*2);
    _Float16* pvW2p   = (_Float16*)alloc(4096*2);
    _Float16* pvW3p16 = (_Float16*)alloc(2048*2);
    _Float16* foW1p   = (_Float16*)alloc(4096*2);
    _Float16* foW2p16 = (_Float16*)alloc(4096*2);
    _Float16* foW3p16 = (_Float16*)alloc(2048*2);

    pack_kernel<<<16, 256, 0, stream>>>(
        fr_w2, fr_w3, pv_w2, pv_w3, fo_w1, fo_w2, fo_w3,
        frW2p, frW3p16, pvW2p, pvW3p16, foW1p, foW2p16, foW3p16);

    fused_kernel<<<BATCH, 512, 0, stream>>>(
        x, y, fr_w1, fr_b1, fr_b2, fr_b3,
        pv_w1, pv_b1, pv_b2, pv_b3,
        fo_b1, fo_b2, fo_b3, fc_w, fc_b,
        (const half8*)frW2p, (const half4v*)frW3p16,
        (const half8*)pvW2p, (const half4v*)pvW3p16,
        (const half8*)foW1p, (const half4v*)foW2p16, (const half4v*)foW3p16,
        out);
}

// Round 4
// 151.952 us; speedup vs baseline: 1.1337x; 1.1337x over previous
//
#include <hip/hip_runtime.h>

#define BATCH 512
#define NPART 60
#define PFEAT 20
#define SFEAT 14
#define NVTX  5
#define HID   60
#define DE    20
#define DO    24
#define NCLS  2
#define SR    68          // LDS row stride in halves: 34 words -> 2-way banks max

typedef _Float16 half8  __attribute__((ext_vector_type(8)));
typedef _Float16 half4v __attribute__((ext_vector_type(4)));
typedef __fp16   fp16x2 __attribute__((ext_vector_type(2)));
typedef float    f32x4  __attribute__((ext_vector_type(4)));

__device__ __forceinline__ half4v pkcvt4(f32x4 a) {
    fp16x2 lo = __builtin_amdgcn_cvt_pkrtz(a[0], a[1]);
    fp16x2 hi = __builtin_amdgcn_cvt_pkrtz(a[2], a[3]);
    half4v r;
    r[0] = (_Float16)lo[0]; r[1] = (_Float16)lo[1];
    r[2] = (_Float16)hi[0]; r[3] = (_Float16)hi[1];
    return r;
}
__device__ __forceinline__ half4v relu4(half4v a) {
#pragma unroll
    for (int j = 0; j < 4; ++j)
        a[j] = (a[j] > (_Float16)0.f) ? a[j] : (_Float16)0.f;
    return a;
}
__device__ __forceinline__ f32x4 bias4(const float* b, int col4, int lim) {
    f32x4 z = {0.f, 0.f, 0.f, 0.f};
    return (col4 < lim) ? *(const f32x4*)(b + col4) : z;
}

// ---------------------------------------------------------------------------
// Prep kernel: blocks 0-15 pack weight tables (round-11 logic + NEW w1
// operand tables); blocks 16+ transpose/convert x into xp[b][p][32] fp16.
// All P0 operand construction moves here (amortized, memory-bound) so the
// fused kernel's staging phase is pure vector loads + MFMA.
// ---------------------------------------------------------------------------
__global__ __launch_bounds__(256) void prep_kernel(
    const float* __restrict__ x,
    const float* __restrict__ fr_w1, const float* __restrict__ pv_w1,
    const float* __restrict__ fr_w2, const float* __restrict__ fr_w3,
    const float* __restrict__ pv_w2, const float* __restrict__ pv_w3,
    const float* __restrict__ fo_w1, const float* __restrict__ fo_w2,
    const float* __restrict__ fo_w3,
    _Float16* __restrict__ frW2p, _Float16* __restrict__ frW3p16,
    _Float16* __restrict__ pvW2p, _Float16* __restrict__ pvW3p16,
    _Float16* __restrict__ foW1p, _Float16* __restrict__ foW2p16,
    _Float16* __restrict__ foW3p16,
    _Float16* __restrict__ frW1Ap, _Float16* __restrict__ frW1Bp,
    _Float16* __restrict__ pvW1Ap, _Float16* __restrict__ xp)
{
    if (blockIdx.x < 16) {
        int idx = blockIdx.x*256 + threadIdx.x;    // 0..4095
        {   // x32 tables, u<4, kk<2
            int j  = idx & 7;
            int L  = (idx >> 3) & 63;
            int kk = (idx >> 9) & 1;
            int u  = idx >> 10;
            int k  = kk*32 + (L >> 4)*8 + j;
            int n  = u*16 + (L & 15);
            bool ok = (k < HID && n < HID);
            frW2p[idx] = (_Float16)(ok ? fr_w2[k*HID + n] : 0.f);
            pvW2p[idx] = (_Float16)(ok ? pv_w2[k*HID + n] : 0.f);
            foW1p[idx] = (_Float16)(ok ? fo_w1[k*HID + n] : 0.f);
        }
        {   // x16 table, u<4: fo_w2
            int j  = idx & 3;
            int L  = (idx >> 2) & 63;
            int kt = (idx >> 8) & 3;
            int u  = idx >> 10;
            int k  = kt*16 + (L >> 4)*4 + j;
            int n  = u*16 + (L & 15);
            foW2p16[idx] = (_Float16)((k < HID && n < HID) ? fo_w2[k*HID + n] : 0.f);
        }
        if (idx < 2048) {   // x16 tables, u<2: w3
            {
                int j  = idx & 3;
                int L  = (idx >> 2) & 63;
                int kt = (idx >> 8) & 3;
                int u  = idx >> 10;
                int k  = kt*16 + (L >> 4)*4 + j;
                int n  = u*16 + (L & 15);
                frW3p16[idx] = (_Float16)((k < HID && n < DE) ? fr_w3[k*DE + n] : 0.f);
                pvW3p16[idx] = (_Float16)((k < HID && n < DE) ? pv_w3[k*DE + n] : 0.f);
                foW3p16[idx] = (_Float16)((k < HID && n < DO) ? fo_w3[k*DO + n] : 0.f);
            }
            {   // NEW: layer-1 operand tables [u<4][lane<64][j<8]
                int j = idx & 7;
                int L = (idx >> 3) & 63;
                int u = idx >> 9;
                int k = (L >> 4)*8 + j;        // q*8 + j
                int n = u*16 + (L & 15);       // u*16 + ml
                bool ok = (k < PFEAT && n < HID);
                frW1Ap[idx] = (_Float16)(ok ? fr_w1[k*HID + n] : 0.f);
                frW1Bp[idx] = (_Float16)(ok ? fr_w1[(PFEAT + k)*HID + n] : 0.f);
                pvW1Ap[idx] = (_Float16)(ok ? pv_w1[k*HID + n] : 0.f);
            }
        }
    } else {
        // x transpose/convert: xp[b][p][32] fp16 (k<PFEAT real, rest 0)
        int idx = (blockIdx.x - 16)*256 + threadIdx.x;   // 0..BATCH*NPART*4-1
        if (idx < BATCH*NPART*4) {
            int p = idx % NPART;
            int t = idx / NPART;
            int q = t & 3;
            int b = t >> 2;
            half8 v;
#pragma unroll
            for (int j = 0; j < 8; ++j) {
                int k = q*8 + j;
                v[j] = (_Float16)((k < PFEAT) ? x[((size_t)b*PFEAT + k)*NPART + p] : 0.f);
            }
            *(half8*)(xp + ((size_t)b*NPART + p)*32 + q*8) = v;
        }
    }
}

// ---------------------------------------------------------------------------
// Fused network kernel v7: v5 structure (proven 79us) with P0 de-scalarized.
// P0 was ~25% of kernel time (r1 evidence: duplicating staging cost +16us
// device-wide) because every block rebuilt MFMA weight operands and bX
// scalar-by-scalar from global fp32 (~64 scalar loads + ~128 cvt/select VALU
// per wave per task). Now w1 operands and x come pre-packed: one 16B load
// each. P1a/P1b/P2/P3 unchanged from the 79us baseline.
// ---------------------------------------------------------------------------
__global__ __launch_bounds__(512) void fused_kernel(
    const float* __restrict__ y,
    const float* __restrict__ fr_b1,
    const float* __restrict__ fr_b2, const float* __restrict__ fr_b3,
    const float* __restrict__ pv_w1, const float* __restrict__ pv_b1,
    const float* __restrict__ pv_b2, const float* __restrict__ pv_b3,
    const float* __restrict__ fo_b1, const float* __restrict__ fo_b2,
    const float* __restrict__ fo_b3,
    const float* __restrict__ fcw, const float* __restrict__ fcb,
    const half8*  __restrict__ frw2p, const half4v* __restrict__ frw3p16,
    const half8*  __restrict__ pvw2p, const half4v* __restrict__ pvw3p16,
    const half8*  __restrict__ fow1p, const half4v* __restrict__ fow2p16,
    const half4v* __restrict__ fow3p16,
    const half8*  __restrict__ frw1ap, const half8* __restrict__ frw1bp,
    const half8*  __restrict__ pvw1ap, const _Float16* __restrict__ xp,
    float* __restrict__ out)
{
    __shared__ __align__(16) _Float16 sFrA[NPART*SR];     // P2+: aliased as sCin
    __shared__ __align__(16) _Float16 sFrB[NPART*SR];
    __shared__ __align__(16) _Float16 sPvA[NPART*SR];
    __shared__ __align__(16) _Float16 sPvV[NVTX*64];
    __shared__ __align__(16) _Float16 sEpp[NPART*DE];
    __shared__ __align__(16) _Float16 sEpvP[NVTX*NPART*DE];
    __shared__ __align__(16) float    sDsum[4][DO];
    _Float16* sCin = sFrA;

    int bb   = blockIdx.x;
    int wv   = threadIdx.x >> 6;     // 0..7
    int lane = threadIdx.x & 63;
    int ml   = lane & 15;
    int q    = lane >> 4;

    // ================= P0: stage A (pure vector loads + MFMA) ===============
    {
        int tile = wv & 3;
        int row  = 16*tile + ml;
        int rr   = (row < NPART) ? row : 0;
        half8 bX = *(const half8*)(xp + ((size_t)bb*NPART + rr)*32 + q*8);
#pragma unroll
        for (int task = 0; task < 2; ++task) {
            const half8* Wt; const float* bset; _Float16* Ot;
            if (wv < 4) {
                if (task == 0) { Wt = frw1ap; bset = fr_b1;  Ot = sFrA; }
                else           { Wt = pvw1ap; bset = nullptr; Ot = sPvA; }
            } else {
                if (task == 1) break;
                Wt = frw1bp; bset = nullptr; Ot = sFrB;
            }
#pragma unroll
            for (int u = 0; u < 4; ++u) {
                half8 w8 = Wt[u*64 + lane];
                f32x4 acc = bset ? bias4(bset, u*16 + 4*q, HID - 3)
                                 : (f32x4){0.f, 0.f, 0.f, 0.f};
                acc = __builtin_amdgcn_mfma_f32_16x16x32_f16(w8, bX, acc, 0, 0, 0);
                if (row < NPART)
                    *(half4v*)(Ot + row*SR + u*16 + 4*q) = pkcvt4(acc);
            }
        }
        // pvV: 320 outputs, one per thread
        for (int idx = threadIdx.x; idx < NVTX*64; idx += 512) {
            int v = idx >> 6;
            int h = idx & 63;
            float a = 0.f;
            if (h < HID) {
                a = pv_b1[h];
#pragma unroll
                for (int f = 0; f < SFEAT; ++f)
                    a += y[((size_t)bb*SFEAT + f)*NVTX + v] * pv_w1[(PFEAT + f)*HID + h];
            }
            sPvV[idx] = (_Float16)a;
        }
    }
    __syncthreads();

    // ================= P1a: fr-edge groups, r = wv + 8k, t-pair halves ======
    for (int r = wv; r < NPART; r += 8) {
        float s[2][4];
#pragma unroll
        for (int v = 0; v < 2; ++v)
#pragma unroll
            for (int i = 0; i < 4; ++i) s[v][i] = 0.f;

#pragma unroll
        for (int th = 0; th < 2; ++th) {
            half8 bA[2][2];
#pragma unroll
            for (int tl = 0; tl < 2; ++tl) {
                int edge = 16*(2*th + tl) + ml;
                int sr = (edge < NPART-1) ? (edge + (edge >= r)) : 0;
#pragma unroll
                for (int kk = 0; kk < 2; ++kk) {
                    half8 u8 = *(const half8*)(sFrA + r*SR + kk*32 + q*8);
                    half8 v8 = *(const half8*)(sFrB + sr*SR + kk*32 + q*8);
                    half8 s8 = u8 + v8;
#pragma unroll
                    for (int j = 0; j < 8; ++j) {
                        _Float16 vj = s8[j];
                        s8[j] = (vj > (_Float16)0.f) ? vj : (_Float16)0.f;
                    }
                    bA[tl][kk] = s8;
                }
            }
            f32x4 acc3[2][2];
#pragma unroll
            for (int v = 0; v < 2; ++v) {
                f32x4 bi = bias4(fr_b3, v*16 + 4*q, DE - 3);
#pragma unroll
                for (int tl = 0; tl < 2; ++tl) acc3[v][tl] = bi;
            }
#pragma unroll
            for (int u = 0; u < 4; ++u) {
                half8 w0 = frw2p[(u*2 + 0)*64 + lane];
                half8 w1 = frw2p[(u*2 + 1)*64 + lane];
                f32x4 bi2 = bias4(fr_b2, u*16 + 4*q, HID - 3);
                half4v a3u[2];
#pragma unroll
                for (int tl = 0; tl < 2; ++tl) {
                    f32x4 a = bi2;
                    a = __builtin_amdgcn_mfma_f32_16x16x32_f16(w0, bA[tl][0], a, 0, 0, 0);
                    a = __builtin_amdgcn_mfma_f32_16x16x32_f16(w1, bA[tl][1], a, 0, 0, 0);
                    a3u[tl] = relu4(pkcvt4(a));
                }
                half4v w3a = frw3p16[(0*4 + u)*64 + lane];
                half4v w3b = frw3p16[(1*4 + u)*64 + lane];
#pragma unroll
                for (int tl = 0; tl < 2; ++tl) {
                    acc3[0][tl] = __builtin_amdgcn_mfma_f32_16x16x16f16(w3a, a3u[tl], acc3[0][tl], 0, 0, 0);
                    acc3[1][tl] = __builtin_amdgcn_mfma_f32_16x16x16f16(w3b, a3u[tl], acc3[1][tl], 0, 0, 0);
                }
            }
#pragma unroll
            for (int v = 0; v < 2; ++v)
#pragma unroll
                for (int tl = 0; tl < 2; ++tl) {
                    int edge = 16*(2*th + tl) + ml;
                    bool ok = edge < NPART-1;
#pragma unroll
                    for (int i = 0; i < 4; ++i)
                        s[v][i] += ok ? fmaxf(acc3[v][tl][i], 0.f) : 0.f;
                }
        }
        // butterfly over edge lanes -> sEpp[r]
#pragma unroll
        for (int v = 0; v < 2; ++v) {
#pragma unroll
            for (int i = 0; i < 4; ++i) {
                s[v][i] += __shfl_xor(s[v][i], 1);
                s[v][i] += __shfl_xor(s[v][i], 2);
                s[v][i] += __shfl_xor(s[v][i], 4);
                s[v][i] += __shfl_xor(s[v][i], 8);
            }
            int col4 = v*16 + 4*q;
            if (ml == 0 && col4 < DE) {
                f32x4 o = {s[v][0], s[v][1], s[v][2], s[v][3]};
                *(half4v*)(sEpp + r*DE + col4) = pkcvt4(o);
            }
        }
    }

    // ================= P1b: pv groups, gv = wv (waves 0-4), t-pair halves ===
    if (wv < NVTX) {
        int gv = wv;
#pragma unroll
        for (int th = 0; th < 2; ++th) {
            half8 bA[2][2];
#pragma unroll
            for (int tl = 0; tl < 2; ++tl) {
                int p = 16*(2*th + tl) + ml;
                int sr = (p < NPART) ? p : 0;
#pragma unroll
                for (int kk = 0; kk < 2; ++kk) {
                    half8 u8 = *(const half8*)(sPvV + gv*64 + kk*32 + q*8);
                    half8 v8 = *(const half8*)(sPvA + sr*SR + kk*32 + q*8);
                    half8 s8 = u8 + v8;
#pragma unroll
                    for (int j = 0; j < 8; ++j) {
                        _Float16 vj = s8[j];
                        s8[j] = (vj > (_Float16)0.f) ? vj : (_Float16)0.f;
                    }
                    bA[tl][kk] = s8;
                }
            }
            f32x4 acc3[2][2];
#pragma unroll
            for (int v = 0; v < 2; ++v) {
                f32x4 bi = bias4(pv_b3, v*16 + 4*q, DE - 3);
#pragma unroll
                for (int tl = 0; tl < 2; ++tl) acc3[v][tl] = bi;
            }
#pragma unroll
            for (int u = 0; u < 4; ++u) {
                half8 w0 = pvw2p[(u*2 + 0)*64 + lane];
                half8 w1 = pvw2p[(u*2 + 1)*64 + lane];
                f32x4 bi2 = bias4(pv_b2, u*16 + 4*q, HID - 3);
                half4v a3u[2];
#pragma unroll
                for (int tl = 0; tl < 2; ++tl) {
                    f32x4 a = bi2;
                    a = __builtin_amdgcn_mfma_f32_16x16x32_f16(w0, bA[tl][0], a, 0, 0, 0);
                    a = __builtin_amdgcn_mfma_f32_16x16x32_f16(w1, bA[tl][1], a, 0, 0, 0);
                    a3u[tl] = relu4(pkcvt4(a));
                }
                half4v w3a = pvw3p16[(0*4 + u)*64 + lane];
                half4v w3b = pvw3p16[(1*4 + u)*64 + lane];
#pragma unroll
                for (int tl = 0; tl < 2; ++tl) {
                    acc3[0][tl] = __builtin_amdgcn_mfma_f32_16x16x16f16(w3a, a3u[tl], acc3[0][tl], 0, 0, 0);
                    acc3[1][tl] = __builtin_amdgcn_mfma_f32_16x16x16f16(w3b, a3u[tl], acc3[1][tl], 0, 0, 0);
                }
            }
#pragma unroll
            for (int v = 0; v < 2; ++v) {
                int col4 = v*16 + 4*q;
#pragma unroll
                for (int tl = 0; tl < 2; ++tl) {
                    int p = 16*(2*th + tl) + ml;
                    if (p < NPART && col4 < DE) {
                        half4v hv = relu4(pkcvt4(acc3[v][tl]));
                        *(half4v*)(sEpvP + (gv*NPART + p)*DE + col4) = hv;
                    }
                }
            }
        }
    }
    __syncthreads();

    // ================= P2: cin gather into sCin (aliases sFrA) ==============
    for (int idx = threadIdx.x; idx < NPART*64; idx += 512) {
        int p = idx >> 6;
        int k = idx & 63;
        _Float16 v;
        if (k < PFEAT) {
            v = xp[((size_t)bb*NPART + p)*32 + k];
        } else if (k < PFEAT + DE) {
            v = sEpp[p*DE + (k - PFEAT)];
        } else if (k < PFEAT + 2*DE) {
            int c = k - PFEAT - DE;
            float s = 0.f;
#pragma unroll
            for (int g5 = 0; g5 < NVTX; ++g5)
                s += (float)sEpvP[(g5*NPART + p)*DE + c];
            v = (_Float16)s;
        } else {
            v = (_Float16)0.f;
        }
        sCin[p*SR + k] = v;
    }
    __syncthreads();

    // ================= P3: object MLP (waves 0-3, tile = wv) ================
    if (wv < 4) {
        int p = 16*wv + ml;
        int sp = (p < NPART) ? p : 0;
        half8 bC[2];
#pragma unroll
        for (int kk = 0; kk < 2; ++kk)
            bC[kk] = *(const half8*)(sCin + sp*SR + kk*32 + q*8);

        f32x4 acc1[4];
#pragma unroll
        for (int u = 0; u < 4; ++u) {
            acc1[u] = bias4(fo_b1, u*16 + 4*q, HID - 3);
            acc1[u] = __builtin_amdgcn_mfma_f32_16x16x32_f16(fow1p[(u*2 + 0)*64 + lane], bC[0], acc1[u], 0, 0, 0);
            acc1[u] = __builtin_amdgcn_mfma_f32_16x16x32_f16(fow1p[(u*2 + 1)*64 + lane], bC[1], acc1[u], 0, 0, 0);
        }
        half4v a2[4];
#pragma unroll
        for (int u = 0; u < 4; ++u) a2[u] = relu4(pkcvt4(acc1[u]));

        f32x4 acc2[4];
#pragma unroll
        for (int u = 0; u < 4; ++u) {
            acc2[u] = bias4(fo_b2, u*16 + 4*q, HID - 3);
#pragma unroll
            for (int kt = 0; kt < 4; ++kt)
                acc2[u] = __builtin_amdgcn_mfma_f32_16x16x16f16(fow2p16[(u*4 + kt)*64 + lane], a2[kt], acc2[u], 0, 0, 0);
        }
        half4v a3[4];
#pragma unroll
        for (int u = 0; u < 4; ++u) a3[u] = relu4(pkcvt4(acc2[u]));

        f32x4 acc3[2];
#pragma unroll
        for (int v = 0; v < 2; ++v) {
            acc3[v] = bias4(fo_b3, v*16 + 4*q, DO - 3);
#pragma unroll
            for (int u = 0; u < 4; ++u)
                acc3[v] = __builtin_amdgcn_mfma_f32_16x16x16f16(fow3p16[(v*4 + u)*64 + lane], a3[u], acc3[v], 0, 0, 0);
        }
#pragma unroll
        for (int v = 0; v < 2; ++v) {
            float s[4];
            bool ok = p < NPART;
#pragma unroll
            for (int i = 0; i < 4; ++i)
                s[i] = ok ? fmaxf(acc3[v][i], 0.f) : 0.f;
#pragma unroll
            for (int i = 0; i < 4; ++i) {
                s[i] += __shfl_xor(s[i], 1);
                s[i] += __shfl_xor(s[i], 2);
                s[i] += __shfl_xor(s[i], 4);
                s[i] += __shfl_xor(s[i], 8);
            }
            int col4 = v*16 + 4*q;
            if (ml == 0 && col4 < DO) {
                f32x4 o = {s[0], s[1], s[2], s[3]};
                *(f32x4*)(sDsum[wv] + col4) = o;
            }
        }
    }
    __syncthreads();

    // ================= fc head (wave 0) =====================================
    if (wv == 0) {
        float tot = 0.f;
        if (lane < DO) {
#pragma unroll
            for (int w4 = 0; w4 < 4; ++w4) tot += sDsum[w4][lane];
        }
        float p0 = (lane < DO) ? tot * fcw[lane*NCLS + 0] : 0.f;
        float p1 = (lane < DO) ? tot * fcw[lane*NCLS + 1] : 0.f;
#pragma unroll
        for (int d = 1; d <= 16; d <<= 1) {
            p0 += __shfl_xor(p0, d);
            p1 += __shfl_xor(p1, d);
        }
        if (lane == 0) {
            out[bb*NCLS + 0] = p0 + fcb[0];
            out[bb*NCLS + 1] = p1 + fcb[1];
        }
    }
}

// ---------------------------------------------------------------------------
extern "C" void kernel_launch(void* const* d_in, const int* in_sizes, int n_in,
                              void* d_out, int out_size, void* d_ws, size_t ws_size,
                              hipStream_t stream)
{
    const float* x     = (const float*)d_in[0];
    const float* y     = (const float*)d_in[1];
    const float* fr_w1 = (const float*)d_in[2];
    const float* fr_b1 = (const float*)d_in[3];
    const float* fr_w2 = (const float*)d_in[4];
    const float* fr_b2 = (const float*)d_in[5];
    const float* fr_w3 = (const float*)d_in[6];
    const float* fr_b3 = (const float*)d_in[7];
    const float* pv_w1 = (const float*)d_in[8];
    const float* pv_b1 = (const float*)d_in[9];
    const float* pv_w2 = (const float*)d_in[10];
    const float* pv_b2 = (const float*)d_in[11];
    const float* pv_w3 = (const float*)d_in[12];
    const float* pv_b3 = (const float*)d_in[13];
    const float* fo_w1 = (const float*)d_in[14];
    const float* fo_b1 = (const float*)d_in[15];
    const float* fo_w2 = (const float*)d_in[16];
    const float* fo_b2 = (const float*)d_in[17];
    const float* fo_w3 = (const float*)d_in[18];
    const float* fo_b3 = (const float*)d_in[19];
    const float* fc_w  = (const float*)d_in[20];
    const float* fc_b  = (const float*)d_in[21];
    float* out = (float*)d_out;

    char* wsb = (char*)d_ws;
    size_t off = 0;
    auto alloc = [&](size_t bytes) { char* p = wsb + off; off += (bytes + 255) & ~(size_t)255; return p; };

    _Float16* frW2p   = (_Float16*)alloc(4096*2);
    _Float16* frW3p16 = (_Float16*)alloc(2048*2);
    _Float16* pvW2p   = (_Float16*)alloc(4096*2);
    _Float16* pvW3p16 = (_Float16*)alloc(2048*2);
    _Float16* foW1p   = (_Float16*)alloc(4096*2);
    _Float16* foW2p16 = (_Float16*)alloc(4096*2);
    _Float16* foW3p16 = (_Float16*)alloc(2048*2);
    _Float16* frW1Ap  = (_Float16*)alloc(2048*2);
    _Float16* frW1Bp  = (_Float16*)alloc(2048*2);
    _Float16* pvW1Ap  = (_Float16*)alloc(2048*2);
    _Float16* xp      = (_Float16*)alloc((size_t)BATCH*NPART*32*2);

    int xblocks = (BATCH*NPART*4 + 255)/256;      // 480
    prep_kernel<<<16 + xblocks, 256, 0, stream>>>(
        x, fr_w1, pv_w1,
        fr_w2, fr_w3, pv_w2, pv_w3, fo_w1, fo_w2, fo_w3,
        frW2p, frW3p16, pvW2p, pvW3p16, foW1p, foW2p16, foW3p16,
        frW1Ap, frW1Bp, pvW1Ap, xp);

    fused_kernel<<<BATCH, 512, 0, stream>>>(
        y, fr_b1, fr_b2, fr_b3,
        pv_w1, pv_b1, pv_b2, pv_b3,
        fo_b1, fo_b2, fo_b3, fc_w, fc_b,
        (const half8*)frW2p, (const half4v*)frW3p16,
        (const half8*)pvW2p, (const half4v*)pvW3p16,
        (const half8*)foW1p, (const half4v*)foW2p16, (const half4v*)foW3p16,
        (const half8*)frW1Ap, (const half8*)frW1Bp,
        (const half8*)pvW1Ap, xp,
        out);
}

// Round 5
// 150.641 us; speedup vs baseline: 1.1436x; 1.0087x over previous
//
#include <hip/hip_runtime.h>

#define BATCH 512
#define NPART 60
#define PFEAT 20
#define SFEAT 14
#define NVTX  5
#define HID   60
#define DE    20
#define DO    24
#define NCLS  2
#define SR    68          // LDS row stride in halves: 34 words -> 2-way banks max

typedef _Float16 half8  __attribute__((ext_vector_type(8)));
typedef _Float16 half4v __attribute__((ext_vector_type(4)));
typedef __fp16   fp16x2 __attribute__((ext_vector_type(2)));
typedef float    f32x4  __attribute__((ext_vector_type(4)));

__device__ __forceinline__ half4v pkcvt4(f32x4 a) {
    fp16x2 lo = __builtin_amdgcn_cvt_pkrtz(a[0], a[1]);
    fp16x2 hi = __builtin_amdgcn_cvt_pkrtz(a[2], a[3]);
    half4v r;
    r[0] = (_Float16)lo[0]; r[1] = (_Float16)lo[1];
    r[2] = (_Float16)hi[0]; r[3] = (_Float16)hi[1];
    return r;
}
__device__ __forceinline__ half4v relu4(half4v a) {
#pragma unroll
    for (int j = 0; j < 4; ++j)
        a[j] = (a[j] > (_Float16)0.f) ? a[j] : (_Float16)0.f;
    return a;
}
__device__ __forceinline__ f32x4 bias4(const float* b, int col4, int lim) {
    f32x4 z = {0.f, 0.f, 0.f, 0.f};
    return (col4 < lim) ? *(const f32x4*)(b + col4) : z;
}

// ---------------------------------------------------------------------------
// Prep kernel: blocks 0-15 pack weight tables; blocks 16+ transpose/convert x
// into xp[b][q][p][8] fp16 (q = K-quarter). Layout changed from r4's
// [b][p][32] so consecutive threads write consecutive 16B (write-coalesced).
// ---------------------------------------------------------------------------
__global__ __launch_bounds__(256) void prep_kernel(
    const float* __restrict__ x,
    const float* __restrict__ fr_w1, const float* __restrict__ pv_w1,
    const float* __restrict__ fr_w2, const float* __restrict__ fr_w3,
    const float* __restrict__ pv_w2, const float* __restrict__ pv_w3,
    const float* __restrict__ fo_w1, const float* __restrict__ fo_w2,
    const float* __restrict__ fo_w3,
    _Float16* __restrict__ frW2p, _Float16* __restrict__ frW3p16,
    _Float16* __restrict__ pvW2p, _Float16* __restrict__ pvW3p16,
    _Float16* __restrict__ foW1p, _Float16* __restrict__ foW2p16,
    _Float16* __restrict__ foW3p16,
    _Float16* __restrict__ frW1Ap, _Float16* __restrict__ frW1Bp,
    _Float16* __restrict__ pvW1Ap, _Float16* __restrict__ xp)
{
    if (blockIdx.x < 16) {
        int idx = blockIdx.x*256 + threadIdx.x;    // 0..4095
        {   // x32 tables, u<4, kk<2
            int j  = idx & 7;
            int L  = (idx >> 3) & 63;
            int kk = (idx >> 9) & 1;
            int u  = idx >> 10;
            int k  = kk*32 + (L >> 4)*8 + j;
            int n  = u*16 + (L & 15);
            bool ok = (k < HID && n < HID);
            frW2p[idx] = (_Float16)(ok ? fr_w2[k*HID + n] : 0.f);
            pvW2p[idx] = (_Float16)(ok ? pv_w2[k*HID + n] : 0.f);
            foW1p[idx] = (_Float16)(ok ? fo_w1[k*HID + n] : 0.f);
        }
        {   // x16 table, u<4: fo_w2
            int j  = idx & 3;
            int L  = (idx >> 2) & 63;
            int kt = (idx >> 8) & 3;
            int u  = idx >> 10;
            int k  = kt*16 + (L >> 4)*4 + j;
            int n  = u*16 + (L & 15);
            foW2p16[idx] = (_Float16)((k < HID && n < HID) ? fo_w2[k*HID + n] : 0.f);
        }
        if (idx < 2048) {   // x16 tables, u<2: w3
            {
                int j  = idx & 3;
                int L  = (idx >> 2) & 63;
                int kt = (idx >> 8) & 3;
                int u  = idx >> 10;
                int k  = kt*16 + (L >> 4)*4 + j;
                int n  = u*16 + (L & 15);
                frW3p16[idx] = (_Float16)((k < HID && n < DE) ? fr_w3[k*DE + n] : 0.f);
                pvW3p16[idx] = (_Float16)((k < HID && n < DE) ? pv_w3[k*DE + n] : 0.f);
                foW3p16[idx] = (_Float16)((k < HID && n < DO) ? fo_w3[k*DO + n] : 0.f);
            }
            {   // layer-1 operand tables [u<4][lane<64][j<8]
                int j = idx & 7;
                int L = (idx >> 3) & 63;
                int u = idx >> 9;
                int k = (L >> 4)*8 + j;        // q*8 + j
                int n = u*16 + (L & 15);       // u*16 + ml
                bool ok = (k < PFEAT && n < HID);
                frW1Ap[idx] = (_Float16)(ok ? fr_w1[k*HID + n] : 0.f);
                frW1Bp[idx] = (_Float16)(ok ? fr_w1[(PFEAT + k)*HID + n] : 0.f);
                pvW1Ap[idx] = (_Float16)(ok ? pv_w1[k*HID + n] : 0.f);
            }
        }
    } else {
        // x transpose/convert: xp[b][q][p][8] fp16 (k = q*8+j, <PFEAT real)
        int idx = (blockIdx.x - 16)*256 + threadIdx.x;   // 0..BATCH*NPART*4-1
        if (idx < BATCH*NPART*4) {
            int p = idx % NPART;
            int t = idx / NPART;
            int q = t & 3;
            int b = t >> 2;
            half8 v;
#pragma unroll
            for (int j = 0; j < 8; ++j) {
                int k = q*8 + j;
                v[j] = (_Float16)((k < PFEAT) ? x[((size_t)b*PFEAT + k)*NPART + p] : 0.f);
            }
            *(half8*)(xp + (size_t)idx*8) = v;   // idx == (b*4+q)*NPART + p
        }
    }
}

// ---------------------------------------------------------------------------
// Fused network kernel v8: v7 (60.3us) + forced register residency of the
// P1a/P1b packed weight tables. Evidence: r2 proved the compiler SINKS a
// plain source hoist (VGPR stayed 76 -> 16 VMEM reloads per th-unit, ~330
// per wave in P1a); pattern across r1-r4: instruction/latency-event removal
// helps, parallelism doesn't. Fix: asm volatile("" : "+v") keep-alive pins
// the 48 VGPRs (rule-#17 pattern). Biases move to a zero-padded LDS table
// (kills the guarded global load AND the cndmask). u8 receiver-row reads
// hoisted per r (8->2 ds_reads). Masked accumulate via fmac with {0,1}.
// VGPR gate: must stay <=128 (2 blocks/CU @ 4 waves/SIMD), no scratch.
// ---------------------------------------------------------------------------
__global__ __launch_bounds__(512) void fused_kernel(
    const float* __restrict__ y,
    const float* __restrict__ fr_b1,
    const float* __restrict__ fr_b2, const float* __restrict__ fr_b3,
    const float* __restrict__ pv_w1, const float* __restrict__ pv_b1,
    const float* __restrict__ pv_b2, const float* __restrict__ pv_b3,
    const float* __restrict__ fo_b1, const float* __restrict__ fo_b2,
    const float* __restrict__ fo_b3,
    const float* __restrict__ fcw, const float* __restrict__ fcb,
    const half8*  __restrict__ frw2p, const half4v* __restrict__ frw3p16,
    const half8*  __restrict__ pvw2p, const half4v* __restrict__ pvw3p16,
    const half8*  __restrict__ fow1p, const half4v* __restrict__ fow2p16,
    const half4v* __restrict__ fow3p16,
    const half8*  __restrict__ frw1ap, const half8* __restrict__ frw1bp,
    const half8*  __restrict__ pvw1ap, const _Float16* __restrict__ xp,
    float* __restrict__ out)
{
    __shared__ __align__(16) _Float16 sFrA[NPART*SR];     // P2+: aliased as sCin
    __shared__ __align__(16) _Float16 sFrB[NPART*SR];
    __shared__ __align__(16) _Float16 sPvA[NPART*SR];
    __shared__ __align__(16) _Float16 sPvV[NVTX*64];
    __shared__ __align__(16) _Float16 sEpp[NPART*DE];
    __shared__ __align__(16) _Float16 sEpvP[NVTX*NPART*DE];
    __shared__ __align__(16) float    sDsum[4][DO];
    // zero-padded bias table: rows 0:fr_b2 1:fr_b3 2:pv_b2 3:pv_b3
    //                               4:fo_b1 5:fo_b2 6:fo_b3
    __shared__ __align__(16) float    sBias[7*64];
    _Float16* sCin = sFrA;

    int bb   = blockIdx.x;
    int wv   = threadIdx.x >> 6;     // 0..7
    int lane = threadIdx.x & 63;
    int ml   = lane & 15;
    int q    = lane >> 4;

    // ================= P0: stage A (pure vector loads + MFMA) ===============
    {
        // bias table staging (wave-uniform branch per 64-thread group)
        if (threadIdx.x < 448) {
            int arr = wv, i = lane;
            float bv = 0.f;
            if      (arr == 0) { if (i < HID) bv = fr_b2[i]; }
            else if (arr == 1) { if (i < DE)  bv = fr_b3[i]; }
            else if (arr == 2) { if (i < HID) bv = pv_b2[i]; }
            else if (arr == 3) { if (i < DE)  bv = pv_b3[i]; }
            else if (arr == 4) { if (i < HID) bv = fo_b1[i]; }
            else if (arr == 5) { if (i < HID) bv = fo_b2[i]; }
            else               { if (i < DO)  bv = fo_b3[i]; }
            sBias[threadIdx.x] = bv;
        }

        int tile = wv & 3;
        int row  = 16*tile + ml;
        int rr   = (row < NPART) ? row : 0;
        half8 bX = *(const half8*)(xp + (((size_t)bb*4 + q)*NPART + rr)*8);
#pragma unroll
        for (int task = 0; task < 2; ++task) {
            const half8* Wt; const float* bset; _Float16* Ot;
            if (wv < 4) {
                if (task == 0) { Wt = frw1ap; bset = fr_b1;  Ot = sFrA; }
                else           { Wt = pvw1ap; bset = nullptr; Ot = sPvA; }
            } else {
                if (task == 1) break;
                Wt = frw1bp; bset = nullptr; Ot = sFrB;
            }
#pragma unroll
            for (int u = 0; u < 4; ++u) {
                half8 w8 = Wt[u*64 + lane];
                f32x4 acc = bset ? bias4(bset, u*16 + 4*q, HID - 3)
                                 : (f32x4){0.f, 0.f, 0.f, 0.f};
                acc = __builtin_amdgcn_mfma_f32_16x16x32_f16(w8, bX, acc, 0, 0, 0);
                if (row < NPART)
                    *(half4v*)(Ot + row*SR + u*16 + 4*q) = pkcvt4(acc);
            }
        }
        // pvV: 320 outputs, one per thread
        for (int idx = threadIdx.x; idx < NVTX*64; idx += 512) {
            int v = idx >> 6;
            int h = idx & 63;
            float a = 0.f;
            if (h < HID) {
                a = pv_b1[h];
#pragma unroll
                for (int f = 0; f < SFEAT; ++f)
                    a += y[((size_t)bb*SFEAT + f)*NVTX + v] * pv_w1[(PFEAT + f)*HID + h];
            }
            sPvV[idx] = (_Float16)a;
        }
    }
    __syncthreads();

    // ================= P1a: fr-edge groups, r = wv + 8k, pinned weights =====
    {
        half8  w2r[8];
        half4v w3r[8];
#pragma unroll
        for (int t = 0; t < 8; ++t) w2r[t] = frw2p[t*64 + lane];
#pragma unroll
        for (int t = 0; t < 8; ++t) w3r[t] = frw3p16[t*64 + lane];
#pragma unroll
        for (int t = 0; t < 8; ++t) {
            asm volatile("" : "+v"(w2r[t]));
            asm volatile("" : "+v"(w3r[t]));
        }

        for (int r = wv; r < NPART; r += 8) {
            half8 u8k0 = *(const half8*)(sFrA + r*SR + q*8);
            half8 u8k1 = *(const half8*)(sFrA + r*SR + 32 + q*8);
            float s[2][4];
#pragma unroll
            for (int v = 0; v < 2; ++v)
#pragma unroll
                for (int i = 0; i < 4; ++i) s[v][i] = 0.f;

#pragma unroll
            for (int th = 0; th < 2; ++th) {
                half8 bA[2][2];
                float okf[2];
#pragma unroll
                for (int tl = 0; tl < 2; ++tl) {
                    int edge = 16*(2*th + tl) + ml;
                    bool eok = (edge < NPART-1);
                    okf[tl] = eok ? 1.f : 0.f;
                    int sr = eok ? (edge + (edge >= r)) : 0;
#pragma unroll
                    for (int kk = 0; kk < 2; ++kk) {
                        half8 v8 = *(const half8*)(sFrB + sr*SR + kk*32 + q*8);
                        half8 s8 = (kk ? u8k1 : u8k0) + v8;
#pragma unroll
                        for (int j = 0; j < 8; ++j) {
                            _Float16 vj = s8[j];
                            s8[j] = (vj > (_Float16)0.f) ? vj : (_Float16)0.f;
                        }
                        bA[tl][kk] = s8;
                    }
                }
                f32x4 acc3[2][2];
#pragma unroll
                for (int v = 0; v < 2; ++v) {
                    f32x4 bi = *(const f32x4*)(sBias + 1*64 + v*16 + 4*q);
#pragma unroll
                    for (int tl = 0; tl < 2; ++tl) acc3[v][tl] = bi;
                }
#pragma unroll
                for (int u = 0; u < 4; ++u) {
                    half8 w0 = w2r[u*2 + 0];
                    half8 w1 = w2r[u*2 + 1];
                    f32x4 bi2 = *(const f32x4*)(sBias + 0*64 + u*16 + 4*q);
                    half4v a3u[2];
#pragma unroll
                    for (int tl = 0; tl < 2; ++tl) {
                        f32x4 a = bi2;
                        a = __builtin_amdgcn_mfma_f32_16x16x32_f16(w0, bA[tl][0], a, 0, 0, 0);
                        a = __builtin_amdgcn_mfma_f32_16x16x32_f16(w1, bA[tl][1], a, 0, 0, 0);
                        a3u[tl] = relu4(pkcvt4(a));
                    }
                    half4v w3a = w3r[0*4 + u];
                    half4v w3b = w3r[1*4 + u];
#pragma unroll
                    for (int tl = 0; tl < 2; ++tl) {
                        acc3[0][tl] = __builtin_amdgcn_mfma_f32_16x16x16f16(w3a, a3u[tl], acc3[0][tl], 0, 0, 0);
                        acc3[1][tl] = __builtin_amdgcn_mfma_f32_16x16x16f16(w3b, a3u[tl], acc3[1][tl], 0, 0, 0);
                    }
                }
#pragma unroll
                for (int v = 0; v < 2; ++v)
#pragma unroll
                    for (int tl = 0; tl < 2; ++tl)
#pragma unroll
                        for (int i = 0; i < 4; ++i)
                            s[v][i] = fmaf(fmaxf(acc3[v][tl][i], 0.f), okf[tl], s[v][i]);
            }
            // butterfly over edge lanes -> sEpp[r]
#pragma unroll
            for (int v = 0; v < 2; ++v) {
#pragma unroll
                for (int i = 0; i < 4; ++i) {
                    s[v][i] += __shfl_xor(s[v][i], 1);
                    s[v][i] += __shfl_xor(s[v][i], 2);
                    s[v][i] += __shfl_xor(s[v][i], 4);
                    s[v][i] += __shfl_xor(s[v][i], 8);
                }
                int col4 = v*16 + 4*q;
                if (ml == 0 && col4 < DE) {
                    f32x4 o = {s[v][0], s[v][1], s[v][2], s[v][3]};
                    *(half4v*)(sEpp + r*DE + col4) = pkcvt4(o);
                }
            }
        }
    }

    // ================= P1b: pv groups, gv = wv (waves 0-4), pinned weights ==
    if (wv < NVTX) {
        int gv = wv;
        half8  w2r[8];
        half4v w3r[8];
#pragma unroll
        for (int t = 0; t < 8; ++t) w2r[t] = pvw2p[t*64 + lane];
#pragma unroll
        for (int t = 0; t < 8; ++t) w3r[t] = pvw3p16[t*64 + lane];
#pragma unroll
        for (int t = 0; t < 8; ++t) {
            asm volatile("" : "+v"(w2r[t]));
            asm volatile("" : "+v"(w3r[t]));
        }
        half8 u8k0 = *(const half8*)(sPvV + gv*64 + q*8);
        half8 u8k1 = *(const half8*)(sPvV + gv*64 + 32 + q*8);
#pragma unroll
        for (int th = 0; th < 2; ++th) {
            half8 bA[2][2];
#pragma unroll
            for (int tl = 0; tl < 2; ++tl) {
                int p = 16*(2*th + tl) + ml;
                int sr = (p < NPART) ? p : 0;
#pragma unroll
                for (int kk = 0; kk < 2; ++kk) {
                    half8 v8 = *(const half8*)(sPvA + sr*SR + kk*32 + q*8);
                    half8 s8 = (kk ? u8k1 : u8k0) + v8;
#pragma unroll
                    for (int j = 0; j < 8; ++j) {
                        _Float16 vj = s8[j];
                        s8[j] = (vj > (_Float16)0.f) ? vj : (_Float16)0.f;
                    }
                    bA[tl][kk] = s8;
                }
            }
            f32x4 acc3[2][2];
#pragma unroll
            for (int v = 0; v < 2; ++v) {
                f32x4 bi = *(const f32x4*)(sBias + 3*64 + v*16 + 4*q);
#pragma unroll
                for (int tl = 0; tl < 2; ++tl) acc3[v][tl] = bi;
            }
#pragma unroll
            for (int u = 0; u < 4; ++u) {
                half8 w0 = w2r[u*2 + 0];
                half8 w1 = w2r[u*2 + 1];
                f32x4 bi2 = *(const f32x4*)(sBias + 2*64 + u*16 + 4*q);
                half4v a3u[2];
#pragma unroll
                for (int tl = 0; tl < 2; ++tl) {
                    f32x4 a = bi2;
                    a = __builtin_amdgcn_mfma_f32_16x16x32_f16(w0, bA[tl][0], a, 0, 0, 0);
                    a = __builtin_amdgcn_mfma_f32_16x16x32_f16(w1, bA[tl][1], a, 0, 0, 0);
                    a3u[tl] = relu4(pkcvt4(a));
                }
                half4v w3a = w3r[0*4 + u];
                half4v w3b = w3r[1*4 + u];
#pragma unroll
                for (int tl = 0; tl < 2; ++tl) {
                    acc3[0][tl] = __builtin_amdgcn_mfma_f32_16x16x16f16(w3a, a3u[tl], acc3[0][tl], 0, 0, 0);
                    acc3[1][tl] = __builtin_amdgcn_mfma_f32_16x16x16f16(w3b, a3u[tl], acc3[1][tl], 0, 0, 0);
                }
            }
#pragma unroll
            for (int v = 0; v < 2; ++v) {
                int col4 = v*16 + 4*q;
#pragma unroll
                for (int tl = 0; tl < 2; ++tl) {
                    int p = 16*(2*th + tl) + ml;
                    if (p < NPART && col4 < DE) {
                        half4v hv = relu4(pkcvt4(acc3[v][tl]));
                        *(half4v*)(sEpvP + (gv*NPART + p)*DE + col4) = hv;
                    }
                }
            }
        }
    }
    __syncthreads();

    // ================= P2: cin gather into sCin (aliases sFrA) ==============
    for (int idx = threadIdx.x; idx < NPART*64; idx += 512) {
        int p = idx >> 6;
        int k = idx & 63;
        _Float16 v;
        if (k < PFEAT) {
            v = xp[(((size_t)bb*4 + (k >> 3))*NPART + p)*8 + (k & 7)];
        } else if (k < PFEAT + DE) {
            v = sEpp[p*DE + (k - PFEAT)];
        } else if (k < PFEAT + 2*DE) {
            int c = k - PFEAT - DE;
            float s = 0.f;
#pragma unroll
            for (int g5 = 0; g5 < NVTX; ++g5)
                s += (float)sEpvP[(g5*NPART + p)*DE + c];
            v = (_Float16)s;
        } else {
            v = (_Float16)0.f;
        }
        sCin[p*SR + k] = v;
    }
    __syncthreads();

    // ================= P3: object MLP (waves 0-3, tile = wv) ================
    if (wv < 4) {
        int p = 16*wv + ml;
        int sp = (p < NPART) ? p : 0;
        half8 bC[2];
#pragma unroll
        for (int kk = 0; kk < 2; ++kk)
            bC[kk] = *(const half8*)(sCin + sp*SR + kk*32 + q*8);

        f32x4 acc1[4];
#pragma unroll
        for (int u = 0; u < 4; ++u) {
            acc1[u] = *(const f32x4*)(sBias + 4*64 + u*16 + 4*q);
            acc1[u] = __builtin_amdgcn_mfma_f32_16x16x32_f16(fow1p[(u*2 + 0)*64 + lane], bC[0], acc1[u], 0, 0, 0);
            acc1[u] = __builtin_amdgcn_mfma_f32_16x16x32_f16(fow1p[(u*2 + 1)*64 + lane], bC[1], acc1[u], 0, 0, 0);
        }
        half4v a2[4];
#pragma unroll
        for (int u = 0; u < 4; ++u) a2[u] = relu4(pkcvt4(acc1[u]));

        f32x4 acc2[4];
#pragma unroll
        for (int u = 0; u < 4; ++u) {
            acc2[u] = *(const f32x4*)(sBias + 5*64 + u*16 + 4*q);
#pragma unroll
            for (int kt = 0; kt < 4; ++kt)
                acc2[u] = __builtin_amdgcn_mfma_f32_16x16x16f16(fow2p16[(u*4 + kt)*64 + lane], a2[kt], acc2[u], 0, 0, 0);
        }
        half4v a3[4];
#pragma unroll
        for (int u = 0; u < 4; ++u) a3[u] = relu4(pkcvt4(acc2[u]));

        f32x4 acc3[2];
#pragma unroll
        for (int v = 0; v < 2; ++v) {
            acc3[v] = *(const f32x4*)(sBias + 6*64 + v*16 + 4*q);
#pragma unroll
            for (int u = 0; u < 4; ++u)
                acc3[v] = __builtin_amdgcn_mfma_f32_16x16x16f16(fow3p16[(v*4 + u)*64 + lane], a3[u], acc3[v], 0, 0, 0);
        }
#pragma unroll
        for (int v = 0; v < 2; ++v) {
            float s[4];
            bool ok = p < NPART;
#pragma unroll
            for (int i = 0; i < 4; ++i)
                s[i] = ok ? fmaxf(acc3[v][i], 0.f) : 0.f;
#pragma unroll
            for (int i = 0; i < 4; ++i) {
                s[i] += __shfl_xor(s[i], 1);
                s[i] += __shfl_xor(s[i], 2);
                s[i] += __shfl_xor(s[i], 4);
                s[i] += __shfl_xor(s[i], 8);
            }
            int col4 = v*16 + 4*q;
            if (ml == 0 && col4 < DO) {
                f32x4 o = {s[0], s[1], s[2], s[3]};
                *(f32x4*)(sDsum[wv] + col4) = o;
            }
        }
    }
    __syncthreads();

    // ================= fc head (wave 0) =====================================
    if (wv == 0) {
        float tot = 0.f;
        if (lane < DO) {
#pragma unroll
            for (int w4 = 0; w4 < 4; ++w4) tot += sDsum[w4][lane];
        }
        float p0 = (lane < DO) ? tot * fcw[lane*NCLS + 0] : 0.f;
        float p1 = (lane < DO) ? tot * fcw[lane*NCLS + 1] : 0.f;
#pragma unroll
        for (int d = 1; d <= 16; d <<= 1) {
            p0 += __shfl_xor(p0, d);
            p1 += __shfl_xor(p1, d);
        }
        if (lane == 0) {
            out[bb*NCLS + 0] = p0 + fcb[0];
            out[bb*NCLS + 1] = p1 + fcb[1];
        }
    }
}

// ---------------------------------------------------------------------------
extern "C" void kernel_launch(void* const* d_in, const int* in_sizes, int n_in,
                              void* d_out, int out_size, void* d_ws, size_t ws_size,
                              hipStream_t stream)
{
    const float* x     = (const float*)d_in[0];
    const float* y     = (const float*)d_in[1];
    const float* fr_w1 = (const float*)d_in[2];
    const float* fr_b1 = (const float*)d_in[3];
    const float* fr_w2 = (const float*)d_in[4];
    const float* fr_b2 = (const float*)d_in[5];
    const float* fr_w3 = (const float*)d_in[6];
    const float* fr_b3 = (const float*)d_in[7];
    const float* pv_w1 = (const float*)d_in[8];
    const float* pv_b1 = (const float*)d_in[9];
    const float* pv_w2 = (const float*)d_in[10];
    const float* pv_b2 = (const float*)d_in[11];
    const float* pv_w3 = (const float*)d_in[12];
    const float* pv_b3 = (const float*)d_in[13];
    const float* fo_w1 = (const float*)d_in[14];
    const float* fo_b1 = (const float*)d_in[15];
    const float* fo_w2 = (const float*)d_in[16];
    const float* fo_b2 = (const float*)d_in[17];
    const float* fo_w3 = (const float*)d_in[18];
    const float* fo_b3 = (const float*)d_in[19];
    const float* fc_w  = (const float*)d_in[20];
    const float* fc_b  = (const float*)d_in[21];
    float* out = (float*)d_out;

    char* wsb = (char*)d_ws;
    size_t off = 0;
    auto alloc = [&](size_t bytes) { char* p = wsb + off; off += (bytes + 255) & ~(size_t)255; return p; };

    _Float16* frW2p   = (_Float16*)alloc(4096*2);
    _Float16* frW3p16 = (_Float16*)alloc(2048*2);
    _Float16* pvW2p   = (_Float16*)alloc(4096*2);
    _Float16* pvW3p16 = (_Float16*)alloc(2048*2);
    _Float16* foW1p   = (_Float16*)alloc(4096*2);
    _Float16* foW2p16 = (_Float16*)alloc(4096*2);
    _Float16* foW3p16 = (_Float16*)alloc(2048*2);
    _Float16* frW1Ap  = (_Float16*)alloc(2048*2);
    _Float16* frW1Bp  = (_Float16*)alloc(2048*2);
    _Float16* pvW1Ap  = (_Float16*)alloc(2048*2);
    _Float16* xp      = (_Float16*)alloc((size_t)BATCH*NPART*32*2);

    int xblocks = (BATCH*NPART*4 + 255)/256;      // 480
    prep_kernel<<<16 + xblocks, 256, 0, stream>>>(
        x, fr_w1, pv_w1,
        fr_w2, fr_w3, pv_w2, pv_w3, fo_w1, fo_w2, fo_w3,
        frW2p, frW3p16, pvW2p, pvW3p16, foW1p, foW2p16, foW3p16,
        frW1Ap, frW1Bp, pvW1Ap, xp);

    fused_kernel<<<BATCH, 512, 0, stream>>>(
        y, fr_b1, fr_b2, fr_b3,
        pv_w1, pv_b1, pv_b2, pv_b3,
        fo_b1, fo_b2, fo_b3, fc_w, fc_b,
        (const half8*)frW2p, (const half4v*)frW3p16,
        (const half8*)pvW2p, (const half4v*)pvW3p16,
        (const half8*)foW1p, (const half4v*)foW2p16, (const half4v*)foW3p16,
        (const half8*)frW1Ap, (const half8*)frW1Bp,
        (const half8*)pvW1Ap, xp,
        out);
}

// Round 6
// 145.347 us; speedup vs baseline: 1.1852x; 1.0364x over previous
//
#include <hip/hip_runtime.h>

#define BATCH 512
#define NPART 60
#define PFEAT 20
#define SFEAT 14
#define NVTX  5
#define HID   60
#define DE    20
#define DO    24
#define NCLS  2
#define SR    68          // LDS row stride in halves: 34 words -> 2-way banks max

typedef _Float16 half8  __attribute__((ext_vector_type(8)));
typedef _Float16 half4v __attribute__((ext_vector_type(4)));
typedef __fp16   fp16x2 __attribute__((ext_vector_type(2)));
typedef float    f32x4  __attribute__((ext_vector_type(4)));

__device__ __forceinline__ half4v pkcvt4(f32x4 a) {
    fp16x2 lo = __builtin_amdgcn_cvt_pkrtz(a[0], a[1]);
    fp16x2 hi = __builtin_amdgcn_cvt_pkrtz(a[2], a[3]);
    half4v r;
    r[0] = (_Float16)lo[0]; r[1] = (_Float16)lo[1];
    r[2] = (_Float16)hi[0]; r[3] = (_Float16)hi[1];
    return r;
}
__device__ __forceinline__ half4v relu4(half4v a) {
#pragma unroll
    for (int j = 0; j < 4; ++j)
        a[j] = (a[j] > (_Float16)0.f) ? a[j] : (_Float16)0.f;
    return a;
}

// ---------------------------------------------------------------------------
// Prep kernel with BIAS-AS-K-ROW folding: every packed table gets its bias
// vector stored at k-row 60 (layer1: k-row 20), and the activation pad
// column 60 (layer1: 20) is forced to 1.0 so relu passes it through.
// The fused kernel then never reads a bias: MFMA adds it. Also n=60 output
// columns of intermediate layers get a 1.0 "carry" entry so the constant
// propagates through deeper layers.
// ---------------------------------------------------------------------------
__global__ __launch_bounds__(256) void prep_kernel(
    const float* __restrict__ x,
    const float* __restrict__ fr_w1, const float* __restrict__ fr_b1,
    const float* __restrict__ pv_w1,
    const float* __restrict__ fr_w2, const float* __restrict__ fr_b2,
    const float* __restrict__ fr_w3, const float* __restrict__ fr_b3,
    const float* __restrict__ pv_w2, const float* __restrict__ pv_b2,
    const float* __restrict__ pv_w3, const float* __restrict__ pv_b3,
    const float* __restrict__ fo_w1, const float* __restrict__ fo_b1,
    const float* __restrict__ fo_w2, const float* __restrict__ fo_b2,
    const float* __restrict__ fo_w3, const float* __restrict__ fo_b3,
    _Float16* __restrict__ frW2p, _Float16* __restrict__ frW3p16,
    _Float16* __restrict__ pvW2p, _Float16* __restrict__ pvW3p16,
    _Float16* __restrict__ foW1p, _Float16* __restrict__ foW2p16,
    _Float16* __restrict__ foW3p16,
    _Float16* __restrict__ frW1Ap, _Float16* __restrict__ frW1Bp,
    _Float16* __restrict__ pvW1Ap, _Float16* __restrict__ xp)
{
    if (blockIdx.x < 16) {
        int idx = blockIdx.x*256 + threadIdx.x;    // 0..4095
        {   // x32 A-tables [u<4][kk<2 in k][lane][8]: k = kk*32+q*8+j
            int j  = idx & 7;
            int L  = (idx >> 3) & 63;
            int kk = (idx >> 9) & 1;
            int u  = idx >> 10;
            int k  = kk*32 + (L >> 4)*8 + j;
            int n  = u*16 + (L & 15);
            float v2f = 0.f, v2p = 0.f, v1o = 0.f;
            if (k < HID && n < HID) {
                v2f = fr_w2[k*HID + n];
                v2p = pv_w2[k*HID + n];
                v1o = fo_w1[k*HID + n];
            } else if (k == HID) {          // bias row
                if (n < HID)      { v2f = fr_b2[n]; v2p = pv_b2[n]; v1o = fo_b1[n]; }
                else if (n == HID){ v2f = 1.f;      v2p = 1.f;      v1o = 1.f; }  // carry
            }
            frW2p[idx] = (_Float16)v2f;
            pvW2p[idx] = (_Float16)v2p;
            foW1p[idx] = (_Float16)v1o;
        }
        {   // x16 A-table, u<4: fo_w2; k = kt*16+q*4+j
            int j  = idx & 3;
            int L  = (idx >> 2) & 63;
            int kt = (idx >> 8) & 3;
            int u  = idx >> 10;
            int k  = kt*16 + (L >> 4)*4 + j;
            int n  = u*16 + (L & 15);
            float v = 0.f;
            if (k < HID && n < HID)        v = fo_w2[k*HID + n];
            else if (k == HID) {
                if (n < HID)       v = fo_b2[n];
                else if (n == HID) v = 1.f;                          // carry
            }
            foW2p16[idx] = (_Float16)v;
        }
        if (idx < 2048) {   // x16 tables, u<2: w3 (+ bias rows)
            {
                int j  = idx & 3;
                int L  = (idx >> 2) & 63;
                int kt = (idx >> 8) & 3;
                int u  = idx >> 10;
                int k  = kt*16 + (L >> 4)*4 + j;
                int n  = u*16 + (L & 15);
                float vf = 0.f, vp = 0.f, vo = 0.f;
                if (k < HID) {
                    if (n < DE) { vf = fr_w3[k*DE + n]; vp = pv_w3[k*DE + n]; }
                    if (n < DO)   vo = fo_w3[k*DO + n];
                } else if (k == HID) {      // bias row
                    if (n < DE) { vf = fr_b3[n]; vp = pv_b3[n]; }
                    if (n < DO)   vo = fo_b3[n];
                }
                frW3p16[idx] = (_Float16)vf;
                pvW3p16[idx] = (_Float16)vp;
                foW3p16[idx] = (_Float16)vo;
            }
            {   // layer-1 operand tables [u<4][lane][8]: k = q*8+j (<32)
                int j = idx & 7;
                int L = (idx >> 3) & 63;
                int u = idx >> 9;
                int k = (L >> 4)*8 + j;
                int n = u*16 + (L & 15);
                float va = 0.f, vb = 0.f, vpv = 0.f;
                if (k < PFEAT && n < HID) {
                    va  = fr_w1[k*HID + n];
                    vb  = fr_w1[(PFEAT + k)*HID + n];
                    vpv = pv_w1[k*HID + n];
                } else if (k == PFEAT) {    // bias row (A side only)
                    if (n < HID)       va = fr_b1[n];
                    else if (n == HID) va = 1.f;                     // carry in sFrA
                    // vb stays 0 (sFrB col60 = 0), vpv stays 0 (bias on V side)
                }
                frW1Ap[idx] = (_Float16)va;
                frW1Bp[idx] = (_Float16)vb;
                pvW1Ap[idx] = (_Float16)vpv;
            }
        }
    } else {
        // x transpose/convert: xp[b][q][p][8] fp16; k==PFEAT column = 1.0
        int idx = (blockIdx.x - 16)*256 + threadIdx.x;   // 0..BATCH*NPART*4-1
        if (idx < BATCH*NPART*4) {
            int p = idx % NPART;
            int t = idx / NPART;
            int q = t & 3;
            int b = t >> 2;
            half8 v;
#pragma unroll
            for (int j = 0; j < 8; ++j) {
                int k = q*8 + j;
                float f = 0.f;
                if (k < PFEAT)       f = x[((size_t)b*PFEAT + k)*NPART + p];
                else if (k == PFEAT) f = 1.f;                        // bias hook
                v[j] = (_Float16)f;
            }
            *(half8*)(xp + (size_t)idx*8) = v;   // idx == (b*4+q)*NPART + p
        }
    }
}

// ---------------------------------------------------------------------------
// Fused network kernel v9: v8 (57.4us) + bias-as-K-row folding. Diagnosis:
// per-CU DS pipe ~75% occupied (450 DS instr/wave x 16 waves; r1 proved a
// shared per-CU pipe saturates: time scales with work, not waves). Bias
// ds_reads were 6 b128/th-unit -> now 0; every MFMA chain starts from a
// zero accumulator (no load at chain head); sBias gone.
// ---------------------------------------------------------------------------
__global__ __launch_bounds__(512) void fused_kernel(
    const float* __restrict__ y,
    const float* __restrict__ pv_w1, const float* __restrict__ pv_b1,
    const float* __restrict__ fcw, const float* __restrict__ fcb,
    const half8*  __restrict__ frw2p, const half4v* __restrict__ frw3p16,
    const half8*  __restrict__ pvw2p, const half4v* __restrict__ pvw3p16,
    const half8*  __restrict__ fow1p, const half4v* __restrict__ fow2p16,
    const half4v* __restrict__ fow3p16,
    const half8*  __restrict__ frw1ap, const half8* __restrict__ frw1bp,
    const half8*  __restrict__ pvw1ap, const _Float16* __restrict__ xp,
    float* __restrict__ out)
{
    __shared__ __align__(16) _Float16 sFrA[NPART*SR];     // P2+: aliased as sCin
    __shared__ __align__(16) _Float16 sFrB[NPART*SR];
    __shared__ __align__(16) _Float16 sPvA[NPART*SR];
    __shared__ __align__(16) _Float16 sPvV[NVTX*64];
    __shared__ __align__(16) _Float16 sEpp[NPART*DE];
    __shared__ __align__(16) _Float16 sEpvP[NVTX*NPART*DE];
    __shared__ __align__(16) float    sDsum[4][DO];
    _Float16* sCin = sFrA;

    const f32x4 z4 = {0.f, 0.f, 0.f, 0.f};

    int bb   = blockIdx.x;
    int wv   = threadIdx.x >> 6;     // 0..7
    int lane = threadIdx.x & 63;
    int ml   = lane & 15;
    int q    = lane >> 4;

    // ================= P0: stage A (pure vector loads + MFMA, no biases) ====
    {
        int tile = wv & 3;
        int row  = 16*tile + ml;
        int rr   = (row < NPART) ? row : 0;
        half8 bX = *(const half8*)(xp + (((size_t)bb*4 + q)*NPART + rr)*8);
#pragma unroll
        for (int task = 0; task < 2; ++task) {
            const half8* Wt; _Float16* Ot;
            if (wv < 4) {
                if (task == 0) { Wt = frw1ap; Ot = sFrA; }
                else           { Wt = pvw1ap; Ot = sPvA; }
            } else {
                if (task == 1) break;
                Wt = frw1bp; Ot = sFrB;
            }
#pragma unroll
            for (int u = 0; u < 4; ++u) {
                half8 w8 = Wt[u*64 + lane];
                f32x4 acc = z4;
                acc = __builtin_amdgcn_mfma_f32_16x16x32_f16(w8, bX, acc, 0, 0, 0);
                if (row < NPART)
                    *(half4v*)(Ot + row*SR + u*16 + 4*q) = pkcvt4(acc);
            }
        }
        // pvV: 320 outputs, one per thread; col 60 = 1.0 (bias hook)
        for (int idx = threadIdx.x; idx < NVTX*64; idx += 512) {
            int v = idx >> 6;
            int h = idx & 63;
            float a;
            if (h < HID) {
                a = pv_b1[h];
#pragma unroll
                for (int f = 0; f < SFEAT; ++f)
                    a += y[((size_t)bb*SFEAT + f)*NVTX + v] * pv_w1[(PFEAT + f)*HID + h];
            } else {
                a = (h == HID) ? 1.f : 0.f;
            }
            sPvV[idx] = (_Float16)a;
        }
    }
    __syncthreads();

    // ================= P1a: fr-edge groups, r = wv + 8k, pinned weights =====
    {
        half8  w2r[8];
        half4v w3r[8];
#pragma unroll
        for (int t = 0; t < 8; ++t) w2r[t] = frw2p[t*64 + lane];
#pragma unroll
        for (int t = 0; t < 8; ++t) w3r[t] = frw3p16[t*64 + lane];
#pragma unroll
        for (int t = 0; t < 8; ++t) {
            asm volatile("" : "+v"(w2r[t]));
            asm volatile("" : "+v"(w3r[t]));
        }

        for (int r = wv; r < NPART; r += 8) {
            half8 u8k0 = *(const half8*)(sFrA + r*SR + q*8);
            half8 u8k1 = *(const half8*)(sFrA + r*SR + 32 + q*8);
            float s[2][4];
#pragma unroll
            for (int v = 0; v < 2; ++v)
#pragma unroll
                for (int i = 0; i < 4; ++i) s[v][i] = 0.f;

#pragma unroll
            for (int th = 0; th < 2; ++th) {
                half8 bA[2][2];
                float okf[2];
#pragma unroll
                for (int tl = 0; tl < 2; ++tl) {
                    int edge = 16*(2*th + tl) + ml;
                    bool eok = (edge < NPART-1);
                    okf[tl] = eok ? 1.f : 0.f;
                    int sr = eok ? (edge + (edge >= r)) : 0;
#pragma unroll
                    for (int kk = 0; kk < 2; ++kk) {
                        half8 v8 = *(const half8*)(sFrB + sr*SR + kk*32 + q*8);
                        half8 s8 = (kk ? u8k1 : u8k0) + v8;
#pragma unroll
                        for (int j = 0; j < 8; ++j) {
                            _Float16 vj = s8[j];
                            s8[j] = (vj > (_Float16)0.f) ? vj : (_Float16)0.f;
                        }
                        bA[tl][kk] = s8;
                    }
                }
                f32x4 acc3[2][2];
#pragma unroll
                for (int v = 0; v < 2; ++v)
#pragma unroll
                    for (int tl = 0; tl < 2; ++tl) acc3[v][tl] = z4;
#pragma unroll
                for (int u = 0; u < 4; ++u) {
                    half8 w0 = w2r[u*2 + 0];
                    half8 w1 = w2r[u*2 + 1];
                    half4v a3u[2];
#pragma unroll
                    for (int tl = 0; tl < 2; ++tl) {
                        f32x4 a = z4;
                        a = __builtin_amdgcn_mfma_f32_16x16x32_f16(w0, bA[tl][0], a, 0, 0, 0);
                        a = __builtin_amdgcn_mfma_f32_16x16x32_f16(w1, bA[tl][1], a, 0, 0, 0);
                        a3u[tl] = relu4(pkcvt4(a));
                    }
                    half4v w3a = w3r[0*4 + u];
                    half4v w3b = w3r[1*4 + u];
#pragma unroll
                    for (int tl = 0; tl < 2; ++tl) {
                        acc3[0][tl] = __builtin_amdgcn_mfma_f32_16x16x16f16(w3a, a3u[tl], acc3[0][tl], 0, 0, 0);
                        acc3[1][tl] = __builtin_amdgcn_mfma_f32_16x16x16f16(w3b, a3u[tl], acc3[1][tl], 0, 0, 0);
                    }
                }
#pragma unroll
                for (int v = 0; v < 2; ++v)
#pragma unroll
                    for (int tl = 0; tl < 2; ++tl)
#pragma unroll
                        for (int i = 0; i < 4; ++i)
                            s[v][i] = fmaf(fmaxf(acc3[v][tl][i], 0.f), okf[tl], s[v][i]);
            }
            // butterfly over edge lanes -> sEpp[r]
#pragma unroll
            for (int v = 0; v < 2; ++v) {
#pragma unroll
                for (int i = 0; i < 4; ++i) {
                    s[v][i] += __shfl_xor(s[v][i], 1);
                    s[v][i] += __shfl_xor(s[v][i], 2);
                    s[v][i] += __shfl_xor(s[v][i], 4);
                    s[v][i] += __shfl_xor(s[v][i], 8);
                }
                int col4 = v*16 + 4*q;
                if (ml == 0 && col4 < DE) {
                    f32x4 o = {s[v][0], s[v][1], s[v][2], s[v][3]};
                    *(half4v*)(sEpp + r*DE + col4) = pkcvt4(o);
                }
            }
        }
    }

    // ================= P1b: pv groups, gv = wv (waves 0-4), pinned weights ==
    if (wv < NVTX) {
        int gv = wv;
        half8  w2r[8];
        half4v w3r[8];
#pragma unroll
        for (int t = 0; t < 8; ++t) w2r[t] = pvw2p[t*64 + lane];
#pragma unroll
        for (int t = 0; t < 8; ++t) w3r[t] = pvw3p16[t*64 + lane];
#pragma unroll
        for (int t = 0; t < 8; ++t) {
            asm volatile("" : "+v"(w2r[t]));
            asm volatile("" : "+v"(w3r[t]));
        }
        half8 u8k0 = *(const half8*)(sPvV + gv*64 + q*8);
        half8 u8k1 = *(const half8*)(sPvV + gv*64 + 32 + q*8);
#pragma unroll
        for (int th = 0; th < 2; ++th) {
            half8 bA[2][2];
#pragma unroll
            for (int tl = 0; tl < 2; ++tl) {
                int p = 16*(2*th + tl) + ml;
                int sr = (p < NPART) ? p : 0;
#pragma unroll
                for (int kk = 0; kk < 2; ++kk) {
                    half8 v8 = *(const half8*)(sPvA + sr*SR + kk*32 + q*8);
                    half8 s8 = (kk ? u8k1 : u8k0) + v8;
#pragma unroll
                    for (int j = 0; j < 8; ++j) {
                        _Float16 vj = s8[j];
                        s8[j] = (vj > (_Float16)0.f) ? vj : (_Float16)0.f;
                    }
                    bA[tl][kk] = s8;
                }
            }
            f32x4 acc3[2][2];
#pragma unroll
            for (int v = 0; v < 2; ++v)
#pragma unroll
                for (int tl = 0; tl < 2; ++tl) acc3[v][tl] = z4;
#pragma unroll
            for (int u = 0; u < 4; ++u) {
                half8 w0 = w2r[u*2 + 0];
                half8 w1 = w2r[u*2 + 1];
                half4v a3u[2];
#pragma unroll
                for (int tl = 0; tl < 2; ++tl) {
                    f32x4 a = z4;
                    a = __builtin_amdgcn_mfma_f32_16x16x32_f16(w0, bA[tl][0], a, 0, 0, 0);
                    a = __builtin_amdgcn_mfma_f32_16x16x32_f16(w1, bA[tl][1], a, 0, 0, 0);
                    a3u[tl] = relu4(pkcvt4(a));
                }
                half4v w3a = w3r[0*4 + u];
                half4v w3b = w3r[1*4 + u];
#pragma unroll
                for (int tl = 0; tl < 2; ++tl) {
                    acc3[0][tl] = __builtin_amdgcn_mfma_f32_16x16x16f16(w3a, a3u[tl], acc3[0][tl], 0, 0, 0);
                    acc3[1][tl] = __builtin_amdgcn_mfma_f32_16x16x16f16(w3b, a3u[tl], acc3[1][tl], 0, 0, 0);
                }
            }
#pragma unroll
            for (int v = 0; v < 2; ++v) {
                int col4 = v*16 + 4*q;
#pragma unroll
                for (int tl = 0; tl < 2; ++tl) {
                    int p = 16*(2*th + tl) + ml;
                    if (p < NPART && col4 < DE) {
                        half4v hv = relu4(pkcvt4(acc3[v][tl]));
                        *(half4v*)(sEpvP + (gv*NPART + p)*DE + col4) = hv;
                    }
                }
            }
        }
    }
    __syncthreads();

    // ================= P2: cin gather into sCin (aliases sFrA) ==============
    for (int idx = threadIdx.x; idx < NPART*64; idx += 512) {
        int p = idx >> 6;
        int k = idx & 63;
        _Float16 v;
        if (k < PFEAT) {
            v = xp[(((size_t)bb*4 + (k >> 3))*NPART + p)*8 + (k & 7)];
        } else if (k < PFEAT + DE) {
            v = sEpp[p*DE + (k - PFEAT)];
        } else if (k < PFEAT + 2*DE) {
            int c = k - PFEAT - DE;
            float s = 0.f;
#pragma unroll
            for (int g5 = 0; g5 < NVTX; ++g5)
                s += (float)sEpvP[(g5*NPART + p)*DE + c];
            v = (_Float16)s;
        } else {
            v = (k == HID) ? (_Float16)1.f : (_Float16)0.f;   // bias hook
        }
        sCin[p*SR + k] = v;
    }
    __syncthreads();

    // ================= P3: object MLP (waves 0-3, tile = wv) ================
    if (wv < 4) {
        int p = 16*wv + ml;
        int sp = (p < NPART) ? p : 0;
        half8 bC[2];
#pragma unroll
        for (int kk = 0; kk < 2; ++kk)
            bC[kk] = *(const half8*)(sCin + sp*SR + kk*32 + q*8);

        f32x4 acc1[4];
#pragma unroll
        for (int u = 0; u < 4; ++u) {
            acc1[u] = z4;
            acc1[u] = __builtin_amdgcn_mfma_f32_16x16x32_f16(fow1p[(u*2 + 0)*64 + lane], bC[0], acc1[u], 0, 0, 0);
            acc1[u] = __builtin_amdgcn_mfma_f32_16x16x32_f16(fow1p[(u*2 + 1)*64 + lane], bC[1], acc1[u], 0, 0, 0);
        }
        half4v a2[4];
#pragma unroll
        for (int u = 0; u < 4; ++u) a2[u] = relu4(pkcvt4(acc1[u]));

        f32x4 acc2[4];
#pragma unroll
        for (int u = 0; u < 4; ++u) {
            acc2[u] = z4;
#pragma unroll
            for (int kt = 0; kt < 4; ++kt)
                acc2[u] = __builtin_amdgcn_mfma_f32_16x16x16f16(fow2p16[(u*4 + kt)*64 + lane], a2[kt], acc2[u], 0, 0, 0);
        }
        half4v a3[4];
#pragma unroll
        for (int u = 0; u < 4; ++u) a3[u] = relu4(pkcvt4(acc2[u]));

        f32x4 acc3[2];
#pragma unroll
        for (int v = 0; v < 2; ++v) {
            acc3[v] = z4;
#pragma unroll
            for (int u = 0; u < 4; ++u)
                acc3[v] = __builtin_amdgcn_mfma_f32_16x16x16f16(fow3p16[(v*4 + u)*64 + lane], a3[u], acc3[v], 0, 0, 0);
        }
#pragma unroll
        for (int v = 0; v < 2; ++v) {
            float s[4];
            bool ok = p < NPART;
#pragma unroll
            for (int i = 0; i < 4; ++i)
                s[i] = ok ? fmaxf(acc3[v][i], 0.f) : 0.f;
#pragma unroll
            for (int i = 0; i < 4; ++i) {
                s[i] += __shfl_xor(s[i], 1);
                s[i] += __shfl_xor(s[i], 2);
                s[i] += __shfl_xor(s[i], 4);
                s[i] += __shfl_xor(s[i], 8);
            }
            int col4 = v*16 + 4*q;
            if (ml == 0 && col4 < DO) {
                f32x4 o = {s[0], s[1], s[2], s[3]};
                *(f32x4*)(sDsum[wv] + col4) = o;
            }
        }
    }
    __syncthreads();

    // ================= fc head (wave 0) =====================================
    if (wv == 0) {
        float tot = 0.f;
        if (lane < DO) {
#pragma unroll
            for (int w4 = 0; w4 < 4; ++w4) tot += sDsum[w4][lane];
        }
        float p0 = (lane < DO) ? tot * fcw[lane*NCLS + 0] : 0.f;
        float p1 = (lane < DO) ? tot * fcw[lane*NCLS + 1] : 0.f;
#pragma unroll
        for (int d = 1; d <= 16; d <<= 1) {
            p0 += __shfl_xor(p0, d);
            p1 += __shfl_xor(p1, d);
        }
        if (lane == 0) {
            out[bb*NCLS + 0] = p0 + fcb[0];
            out[bb*NCLS + 1] = p1 + fcb[1];
        }
    }
}

// ---------------------------------------------------------------------------
extern "C" void kernel_launch(void* const* d_in, const int* in_sizes, int n_in,
                              void* d_out, int out_size, void* d_ws, size_t ws_size,
                              hipStream_t stream)
{
    const float* x     = (const float*)d_in[0];
    const float* y     = (const float*)d_in[1];
    const float* fr_w1 = (const float*)d_in[2];
    const float* fr_b1 = (const float*)d_in[3];
    const float* fr_w2 = (const float*)d_in[4];
    const float* fr_b2 = (const float*)d_in[5];
    const float* fr_w3 = (const float*)d_in[6];
    const float* fr_b3 = (const float*)d_in[7];
    const float* pv_w1 = (const float*)d_in[8];
    const float* pv_b1 = (const float*)d_in[9];
    const float* pv_w2 = (const float*)d_in[10];
    const float* pv_b2 = (const float*)d_in[11];
    const float* pv_w3 = (const float*)d_in[12];
    const float* pv_b3 = (const float*)d_in[13];
    const float* fo_w1 = (const float*)d_in[14];
    const float* fo_b1 = (const float*)d_in[15];
    const float* fo_w2 = (const float*)d_in[16];
    const float* fo_b2 = (const float*)d_in[17];
    const float* fo_w3 = (const float*)d_in[18];
    const float* fo_b3 = (const float*)d_in[19];
    const float* fc_w  = (const float*)d_in[20];
    const float* fc_b  = (const float*)d_in[21];
    float* out = (float*)d_out;

    char* wsb = (char*)d_ws;
    size_t off = 0;
    auto alloc = [&](size_t bytes) { char* p = wsb + off; off += (bytes + 255) & ~(size_t)255; return p; };

    _Float16* frW2p   = (_Float16*)alloc(4096*2);
    _Float16* frW3p16 = (_Float16*)alloc(2048*2);
    _Float16* pvW2p   = (_Float16*)alloc(4096*2);
    _Float16* pvW3p16 = (_Float16*)alloc(2048*2);
    _Float16* foW1p   = (_Float16*)alloc(4096*2);
    _Float16* foW2p16 = (_Float16*)alloc(4096*2);
    _Float16* foW3p16 = (_Float16*)alloc(2048*2);
    _Float16* frW1Ap  = (_Float16*)alloc(2048*2);
    _Float16* frW1Bp  = (_Float16*)alloc(2048*2);
    _Float16* pvW1Ap  = (_Float16*)alloc(2048*2);
    _Float16* xp      = (_Float16*)alloc((size_t)BATCH*NPART*32*2);

    int xblocks = (BATCH*NPART*4 + 255)/256;      // 480
    prep_kernel<<<16 + xblocks, 256, 0, stream>>>(
        x, fr_w1, fr_b1, pv_w1,
        fr_w2, fr_b2, fr_w3, fr_b3,
        pv_w2, pv_b2, pv_w3, pv_b3,
        fo_w1, fo_b1, fo_w2, fo_b2, fo_w3, fo_b3,
        frW2p, frW3p16, pvW2p, pvW3p16, foW1p, foW2p16, foW3p16,
        frW1Ap, frW1Bp, pvW1Ap, xp);

    fused_kernel<<<BATCH, 512, 0, stream>>>(
        y, pv_w1, pv_b1, fc_w, fc_b,
        (const half8*)frW2p, (const half4v*)frW3p16,
        (const half8*)pvW2p, (const half4v*)pvW3p16,
        (const half8*)foW1p, (const half4v*)foW2p16, (const half4v*)foW3p16,
        (const half8*)frW1Ap, (const half8*)frW1Bp,
        (const half8*)pvW1Ap, xp,
        out);
}

// Round 7
// 131.444 us; speedup vs baseline: 1.3106x; 1.1058x over previous
//
#include <hip/hip_runtime.h>

#define BATCH 512
#define NPART 60
#define PFEAT 20
#define SFEAT 14
#define NVTX  5
#define HID   60
#define DE    20
#define DO    24
#define NCLS  2
#define SR    68          // LDS row stride in halves: 34 words -> 2-way banks max

typedef _Float16 half8  __attribute__((ext_vector_type(8)));
typedef _Float16 half4v __attribute__((ext_vector_type(4)));
typedef __fp16   fp16x2 __attribute__((ext_vector_type(2)));
typedef float    f32x4  __attribute__((ext_vector_type(4)));

__device__ __forceinline__ half4v pkcvt4(f32x4 a) {
    fp16x2 lo = __builtin_amdgcn_cvt_pkrtz(a[0], a[1]);
    fp16x2 hi = __builtin_amdgcn_cvt_pkrtz(a[2], a[3]);
    half4v r;
    r[0] = (_Float16)lo[0]; r[1] = (_Float16)lo[1];
    r[2] = (_Float16)hi[0]; r[3] = (_Float16)hi[1];
    return r;
}
__device__ __forceinline__ half4v relu4(half4v a) {
#pragma unroll
    for (int j = 0; j < 4; ++j)
        a[j] = (a[j] > (_Float16)0.f) ? a[j] : (_Float16)0.f;
    return a;
}

// ---------------------------------------------------------------------------
// Prep kernel (unchanged from r6): bias-as-K-row folding + carry columns.
// NOTE: the w3 tables pack value[k][n] with k=(lane>>4)*4+j, n/col=lane&15 —
// this layout is simultaneously a valid A-operand (row=n) AND B-operand
// (col=n) for mfma_16x16x16f16, which round 7 exploits (operand swap).
// ---------------------------------------------------------------------------
__global__ __launch_bounds__(256) void prep_kernel(
    const float* __restrict__ x,
    const float* __restrict__ fr_w1, const float* __restrict__ fr_b1,
    const float* __restrict__ pv_w1,
    const float* __restrict__ fr_w2, const float* __restrict__ fr_b2,
    const float* __restrict__ fr_w3, const float* __restrict__ fr_b3,
    const float* __restrict__ pv_w2, const float* __restrict__ pv_b2,
    const float* __restrict__ pv_w3, const float* __restrict__ pv_b3,
    const float* __restrict__ fo_w1, const float* __restrict__ fo_b1,
    const float* __restrict__ fo_w2, const float* __restrict__ fo_b2,
    const float* __restrict__ fo_w3, const float* __restrict__ fo_b3,
    _Float16* __restrict__ frW2p, _Float16* __restrict__ frW3p16,
    _Float16* __restrict__ pvW2p, _Float16* __restrict__ pvW3p16,
    _Float16* __restrict__ foW1p, _Float16* __restrict__ foW2p16,
    _Float16* __restrict__ foW3p16,
    _Float16* __restrict__ frW1Ap, _Float16* __restrict__ frW1Bp,
    _Float16* __restrict__ pvW1Ap, _Float16* __restrict__ xp)
{
    if (blockIdx.x < 16) {
        int idx = blockIdx.x*256 + threadIdx.x;    // 0..4095
        {   // x32 A-tables [u<4][kk<2 in k][lane][8]: k = kk*32+q*8+j
            int j  = idx & 7;
            int L  = (idx >> 3) & 63;
            int kk = (idx >> 9) & 1;
            int u  = idx >> 10;
            int k  = kk*32 + (L >> 4)*8 + j;
            int n  = u*16 + (L & 15);
            float v2f = 0.f, v2p = 0.f, v1o = 0.f;
            if (k < HID && n < HID) {
                v2f = fr_w2[k*HID + n];
                v2p = pv_w2[k*HID + n];
                v1o = fo_w1[k*HID + n];
            } else if (k == HID) {          // bias row
                if (n < HID)      { v2f = fr_b2[n]; v2p = pv_b2[n]; v1o = fo_b1[n]; }
                else if (n == HID){ v2f = 1.f;      v2p = 1.f;      v1o = 1.f; }  // carry
            }
            frW2p[idx] = (_Float16)v2f;
            pvW2p[idx] = (_Float16)v2p;
            foW1p[idx] = (_Float16)v1o;
        }
        {   // x16 A-table, u<4: fo_w2; k = kt*16+q*4+j
            int j  = idx & 3;
            int L  = (idx >> 2) & 63;
            int kt = (idx >> 8) & 3;
            int u  = idx >> 10;
            int k  = kt*16 + (L >> 4)*4 + j;
            int n  = u*16 + (L & 15);
            float v = 0.f;
            if (k < HID && n < HID)        v = fo_w2[k*HID + n];
            else if (k == HID) {
                if (n < HID)       v = fo_b2[n];
                else if (n == HID) v = 1.f;                          // carry
            }
            foW2p16[idx] = (_Float16)v;
        }
        if (idx < 2048) {   // x16 tables, u<2: w3 (+ bias rows)
            {
                int j  = idx & 3;
                int L  = (idx >> 2) & 63;
                int kt = (idx >> 8) & 3;
                int u  = idx >> 10;
                int k  = kt*16 + (L >> 4)*4 + j;
                int n  = u*16 + (L & 15);
                float vf = 0.f, vp = 0.f, vo = 0.f;
                if (k < HID) {
                    if (n < DE) { vf = fr_w3[k*DE + n]; vp = pv_w3[k*DE + n]; }
                    if (n < DO)   vo = fo_w3[k*DO + n];
                } else if (k == HID) {      // bias row
                    if (n < DE) { vf = fr_b3[n]; vp = pv_b3[n]; }
                    if (n < DO)   vo = fo_w3 ? fo_b3[n] : 0.f;
                }
                frW3p16[idx] = (_Float16)vf;
                pvW3p16[idx] = (_Float16)vp;
                foW3p16[idx] = (_Float16)vo;
            }
            {   // layer-1 operand tables [u<4][lane][8]: k = q*8+j (<32)
                int j = idx & 7;
                int L = (idx >> 3) & 63;
                int u = idx >> 9;
                int k = (L >> 4)*8 + j;
                int n = u*16 + (L & 15);
                float va = 0.f, vb = 0.f, vpv = 0.f;
                if (k < PFEAT && n < HID) {
                    va  = fr_w1[k*HID + n];
                    vb  = fr_w1[(PFEAT + k)*HID + n];
                    vpv = pv_w1[k*HID + n];
                } else if (k == PFEAT) {    // bias row (A side only)
                    if (n < HID)       va = fr_b1[n];
                    else if (n == HID) va = 1.f;                     // carry in sFrA
                }
                frW1Ap[idx] = (_Float16)va;
                frW1Bp[idx] = (_Float16)vb;
                pvW1Ap[idx] = (_Float16)vpv;
            }
        }
    } else {
        // x transpose/convert: xp[b][q][p][8] fp16; k==PFEAT column = 1.0
        int idx = (blockIdx.x - 16)*256 + threadIdx.x;   // 0..BATCH*NPART*4-1
        if (idx < BATCH*NPART*4) {
            int p = idx % NPART;
            int t = idx / NPART;
            int q = t & 3;
            int b = t >> 2;
            half8 v;
#pragma unroll
            for (int j = 0; j < 8; ++j) {
                int k = q*8 + j;
                float f = 0.f;
                if (k < PFEAT)       f = x[((size_t)b*PFEAT + k)*NPART + p];
                else if (k == PFEAT) f = 1.f;                        // bias hook
                v[j] = (_Float16)f;
            }
            *(half8*)(xp + (size_t)idx*8) = v;   // idx == (b*4+q)*NPART + p
        }
    }
}

// ---------------------------------------------------------------------------
// Fused network kernel v10: v9 (56.2us) + operand-swapped layer-3 MFMA.
// The 32-shuffle/4-step-serial butterfly per r-iteration (~240 DS ops/wave,
// the largest remaining DS-pipe + serial-latency consumer) is replaced by
// computing D[edge][feat] = mfma(a3u, w3) — valid because A/B operand reg
// layouts of mfma_16x16x16f16 are identical, so existing tables/fragments
// swap roles for free. Edge-sum = 4 in-lane adds + xor16/xor32 (2 shuffles).
// Same transform in P3 (object-sum). MFMA count unchanged.
// ---------------------------------------------------------------------------
__global__ __launch_bounds__(512) void fused_kernel(
    const float* __restrict__ y,
    const float* __restrict__ pv_w1, const float* __restrict__ pv_b1,
    const float* __restrict__ fcw, const float* __restrict__ fcb,
    const half8*  __restrict__ frw2p, const half4v* __restrict__ frw3p16,
    const half8*  __restrict__ pvw2p, const half4v* __restrict__ pvw3p16,
    const half8*  __restrict__ fow1p, const half4v* __restrict__ fow2p16,
    const half4v* __restrict__ fow3p16,
    const half8*  __restrict__ frw1ap, const half8* __restrict__ frw1bp,
    const half8*  __restrict__ pvw1ap, const _Float16* __restrict__ xp,
    float* __restrict__ out)
{
    __shared__ __align__(16) _Float16 sFrA[NPART*SR];     // P2+: aliased as sCin
    __shared__ __align__(16) _Float16 sFrB[NPART*SR];
    __shared__ __align__(16) _Float16 sPvA[NPART*SR];
    __shared__ __align__(16) _Float16 sPvV[NVTX*64];
    __shared__ __align__(16) _Float16 sEpp[NPART*DE];
    __shared__ __align__(16) _Float16 sEpvP[NVTX*NPART*DE];
    __shared__ __align__(16) float    sDsum[4][DO];
    _Float16* sCin = sFrA;

    const f32x4 z4 = {0.f, 0.f, 0.f, 0.f};

    int bb   = blockIdx.x;
    int wv   = threadIdx.x >> 6;     // 0..7
    int lane = threadIdx.x & 63;
    int ml   = lane & 15;
    int q    = lane >> 4;

    // ================= P0: stage A (pure vector loads + MFMA, no biases) ====
    {
        int tile = wv & 3;
        int row  = 16*tile + ml;
        int rr   = (row < NPART) ? row : 0;
        half8 bX = *(const half8*)(xp + (((size_t)bb*4 + q)*NPART + rr)*8);
#pragma unroll
        for (int task = 0; task < 2; ++task) {
            const half8* Wt; _Float16* Ot;
            if (wv < 4) {
                if (task == 0) { Wt = frw1ap; Ot = sFrA; }
                else           { Wt = pvw1ap; Ot = sPvA; }
            } else {
                if (task == 1) break;
                Wt = frw1bp; Ot = sFrB;
            }
#pragma unroll
            for (int u = 0; u < 4; ++u) {
                half8 w8 = Wt[u*64 + lane];
                f32x4 acc = z4;
                acc = __builtin_amdgcn_mfma_f32_16x16x32_f16(w8, bX, acc, 0, 0, 0);
                if (row < NPART)
                    *(half4v*)(Ot + row*SR + u*16 + 4*q) = pkcvt4(acc);
            }
        }
        // pvV: 320 outputs, one per thread; col 60 = 1.0 (bias hook)
        for (int idx = threadIdx.x; idx < NVTX*64; idx += 512) {
            int v = idx >> 6;
            int h = idx & 63;
            float a;
            if (h < HID) {
                a = pv_b1[h];
#pragma unroll
                for (int f = 0; f < SFEAT; ++f)
                    a += y[((size_t)bb*SFEAT + f)*NVTX + v] * pv_w1[(PFEAT + f)*HID + h];
            } else {
                a = (h == HID) ? 1.f : 0.f;
            }
            sPvV[idx] = (_Float16)a;
        }
    }
    __syncthreads();

    // ================= P1a: fr-edge groups, swapped layer-3, no butterfly ===
    {
        half8  w2r[8];
        half4v w3r[8];
#pragma unroll
        for (int t = 0; t < 8; ++t) w2r[t] = frw2p[t*64 + lane];
#pragma unroll
        for (int t = 0; t < 8; ++t) w3r[t] = frw3p16[t*64 + lane];
#pragma unroll
        for (int t = 0; t < 8; ++t) {
            asm volatile("" : "+v"(w2r[t]));
            asm volatile("" : "+v"(w3r[t]));
        }
        // chunk-3 output-row mask: edge = 48 + 4q + i valid iff 4q+i < 11
        float ok3[4];
#pragma unroll
        for (int i = 0; i < 4; ++i) ok3[i] = (4*q + i < 11) ? 1.f : 0.f;

        for (int r = wv; r < NPART; r += 8) {
            half8 u8k0 = *(const half8*)(sFrA + r*SR + q*8);
            half8 u8k1 = *(const half8*)(sFrA + r*SR + 32 + q*8);
            float s0 = 0.f, s1 = 0.f;

#pragma unroll
            for (int c = 0; c < 4; ++c) {
                int edge = 16*c + ml;
                bool eok = (edge < NPART-1);
                int sr = eok ? (edge + (edge >= r)) : 0;
                half8 bA0, bA1;
                {
                    half8 v8 = *(const half8*)(sFrB + sr*SR + q*8);
                    half8 s8 = u8k0 + v8;
#pragma unroll
                    for (int j = 0; j < 8; ++j)
                        s8[j] = (s8[j] > (_Float16)0.f) ? s8[j] : (_Float16)0.f;
                    bA0 = s8;
                    v8 = *(const half8*)(sFrB + sr*SR + 32 + q*8);
                    s8 = u8k1 + v8;
#pragma unroll
                    for (int j = 0; j < 8; ++j)
                        s8[j] = (s8[j] > (_Float16)0.f) ? s8[j] : (_Float16)0.f;
                    bA1 = s8;
                }
                half4v a3u[4];
#pragma unroll
                for (int u = 0; u < 4; ++u) {
                    f32x4 a = z4;
                    a = __builtin_amdgcn_mfma_f32_16x16x32_f16(w2r[u*2 + 0], bA0, a, 0, 0, 0);
                    a = __builtin_amdgcn_mfma_f32_16x16x32_f16(w2r[u*2 + 1], bA1, a, 0, 0, 0);
                    a3u[u] = relu4(pkcvt4(a));
                }
                // swapped: D[edge-in-chunk][feat]
                f32x4 e0 = z4, e1 = z4;
#pragma unroll
                for (int u = 0; u < 4; ++u) {
                    e0 = __builtin_amdgcn_mfma_f32_16x16x16f16(a3u[u], w3r[0*4 + u], e0, 0, 0, 0);
                    e1 = __builtin_amdgcn_mfma_f32_16x16x16f16(a3u[u], w3r[1*4 + u], e1, 0, 0, 0);
                }
                if (c < 3) {
#pragma unroll
                    for (int i = 0; i < 4; ++i) {
                        s0 += fmaxf(e0[i], 0.f);
                        s1 += fmaxf(e1[i], 0.f);
                    }
                } else {
#pragma unroll
                    for (int i = 0; i < 4; ++i) {
                        s0 = fmaf(fmaxf(e0[i], 0.f), ok3[i], s0);
                        s1 = fmaf(fmaxf(e1[i], 0.f), ok3[i], s1);
                    }
                }
            }
            // cross-q reduce (2 shuffles each) and scalar store
            s0 += __shfl_xor(s0, 16);
            s1 += __shfl_xor(s1, 16);
            s0 += __shfl_xor(s0, 32);
            s1 += __shfl_xor(s1, 32);
            if (q == 0) {
                sEpp[r*DE + ml] = (_Float16)s0;          // feats 0..15
                if (ml < DE - 16)
                    sEpp[r*DE + 16 + ml] = (_Float16)s1; // feats 16..19
            }
        }
    }

    // ================= P1b: pv groups, gv = wv (waves 0-4), pinned weights ==
    if (wv < NVTX) {
        int gv = wv;
        half8  w2r[8];
        half4v w3r[8];
#pragma unroll
        for (int t = 0; t < 8; ++t) w2r[t] = pvw2p[t*64 + lane];
#pragma unroll
        for (int t = 0; t < 8; ++t) w3r[t] = pvw3p16[t*64 + lane];
#pragma unroll
        for (int t = 0; t < 8; ++t) {
            asm volatile("" : "+v"(w2r[t]));
            asm volatile("" : "+v"(w3r[t]));
        }
        half8 u8k0 = *(const half8*)(sPvV + gv*64 + q*8);
        half8 u8k1 = *(const half8*)(sPvV + gv*64 + 32 + q*8);
#pragma unroll
        for (int th = 0; th < 2; ++th) {
            half8 bA[2][2];
#pragma unroll
            for (int tl = 0; tl < 2; ++tl) {
                int p = 16*(2*th + tl) + ml;
                int sr = (p < NPART) ? p : 0;
#pragma unroll
                for (int kk = 0; kk < 2; ++kk) {
                    half8 v8 = *(const half8*)(sPvA + sr*SR + kk*32 + q*8);
                    half8 s8 = (kk ? u8k1 : u8k0) + v8;
#pragma unroll
                    for (int j = 0; j < 8; ++j) {
                        _Float16 vj = s8[j];
                        s8[j] = (vj > (_Float16)0.f) ? vj : (_Float16)0.f;
                    }
                    bA[tl][kk] = s8;
                }
            }
            f32x4 acc3[2][2];
#pragma unroll
            for (int v = 0; v < 2; ++v)
#pragma unroll
                for (int tl = 0; tl < 2; ++tl) acc3[v][tl] = z4;
#pragma unroll
            for (int u = 0; u < 4; ++u) {
                half8 w0 = w2r[u*2 + 0];
                half8 w1 = w2r[u*2 + 1];
                half4v a3u[2];
#pragma unroll
                for (int tl = 0; tl < 2; ++tl) {
                    f32x4 a = z4;
                    a = __builtin_amdgcn_mfma_f32_16x16x32_f16(w0, bA[tl][0], a, 0, 0, 0);
                    a = __builtin_amdgcn_mfma_f32_16x16x32_f16(w1, bA[tl][1], a, 0, 0, 0);
                    a3u[tl] = relu4(pkcvt4(a));
                }
                half4v w3a = w3r[0*4 + u];
                half4v w3b = w3r[1*4 + u];
#pragma unroll
                for (int tl = 0; tl < 2; ++tl) {
                    acc3[0][tl] = __builtin_amdgcn_mfma_f32_16x16x16f16(w3a, a3u[tl], acc3[0][tl], 0, 0, 0);
                    acc3[1][tl] = __builtin_amdgcn_mfma_f32_16x16x16f16(w3b, a3u[tl], acc3[1][tl], 0, 0, 0);
                }
            }
#pragma unroll
            for (int v = 0; v < 2; ++v) {
                int col4 = v*16 + 4*q;
#pragma unroll
                for (int tl = 0; tl < 2; ++tl) {
                    int p = 16*(2*th + tl) + ml;
                    if (p < NPART && col4 < DE) {
                        half4v hv = relu4(pkcvt4(acc3[v][tl]));
                        *(half4v*)(sEpvP + (gv*NPART + p)*DE + col4) = hv;
                    }
                }
            }
        }
    }
    __syncthreads();

    // ================= P2: cin gather into sCin (aliases sFrA) ==============
    for (int idx = threadIdx.x; idx < NPART*64; idx += 512) {
        int p = idx >> 6;
        int k = idx & 63;
        _Float16 v;
        if (k < PFEAT) {
            v = xp[(((size_t)bb*4 + (k >> 3))*NPART + p)*8 + (k & 7)];
        } else if (k < PFEAT + DE) {
            v = sEpp[p*DE + (k - PFEAT)];
        } else if (k < PFEAT + 2*DE) {
            int c = k - PFEAT - DE;
            float s = 0.f;
#pragma unroll
            for (int g5 = 0; g5 < NVTX; ++g5)
                s += (float)sEpvP[(g5*NPART + p)*DE + c];
            v = (_Float16)s;
        } else {
            v = (k == HID) ? (_Float16)1.f : (_Float16)0.f;   // bias hook
        }
        sCin[p*SR + k] = v;
    }
    __syncthreads();

    // ================= P3: object MLP (waves 0-3), swapped final layer ======
    if (wv < 4) {
        int p = 16*wv + ml;
        int sp = (p < NPART) ? p : 0;
        half8 bC[2];
#pragma unroll
        for (int kk = 0; kk < 2; ++kk)
            bC[kk] = *(const half8*)(sCin + sp*SR + kk*32 + q*8);

        f32x4 acc1[4];
#pragma unroll
        for (int u = 0; u < 4; ++u) {
            acc1[u] = z4;
            acc1[u] = __builtin_amdgcn_mfma_f32_16x16x32_f16(fow1p[(u*2 + 0)*64 + lane], bC[0], acc1[u], 0, 0, 0);
            acc1[u] = __builtin_amdgcn_mfma_f32_16x16x32_f16(fow1p[(u*2 + 1)*64 + lane], bC[1], acc1[u], 0, 0, 0);
        }
        half4v a2[4];
#pragma unroll
        for (int u = 0; u < 4; ++u) a2[u] = relu4(pkcvt4(acc1[u]));

        f32x4 acc2[4];
#pragma unroll
        for (int u = 0; u < 4; ++u) {
            acc2[u] = z4;
#pragma unroll
            for (int kt = 0; kt < 4; ++kt)
                acc2[u] = __builtin_amdgcn_mfma_f32_16x16x16f16(fow2p16[(u*4 + kt)*64 + lane], a2[kt], acc2[u], 0, 0, 0);
        }
        half4v a3[4];
#pragma unroll
        for (int u = 0; u < 4; ++u) a3[u] = relu4(pkcvt4(acc2[u]));

        // swapped: D[p-in-tile][feat]; object-sum = in-lane + xor16/xor32
        f32x4 e0 = z4, e1 = z4;
#pragma unroll
        for (int u = 0; u < 4; ++u) {
            e0 = __builtin_amdgcn_mfma_f32_16x16x16f16(a3[u], fow3p16[(0*4 + u)*64 + lane], e0, 0, 0, 0);
            e1 = __builtin_amdgcn_mfma_f32_16x16x16f16(a3[u], fow3p16[(1*4 + u)*64 + lane], e1, 0, 0, 0);
        }
        // p = 16*wv + 4q + i; invalid only for wv==3 && q==3 (p >= 60)
        float okp = (wv < 3 || q < 3) ? 1.f : 0.f;
        float s0 = 0.f, s1 = 0.f;
#pragma unroll
        for (int i = 0; i < 4; ++i) {
            s0 += fmaxf(e0[i], 0.f);
            s1 += fmaxf(e1[i], 0.f);
        }
        s0 *= okp; s1 *= okp;
        s0 += __shfl_xor(s0, 16);
        s1 += __shfl_xor(s1, 16);
        s0 += __shfl_xor(s0, 32);
        s1 += __shfl_xor(s1, 32);
        if (q == 0) {
            sDsum[wv][ml] = s0;                   // feats 0..15
            if (ml < DO - 16)
                sDsum[wv][16 + ml] = s1;          // feats 16..23
        }
    }
    __syncthreads();

    // ================= fc head (wave 0) =====================================
    if (wv == 0) {
        float tot = 0.f;
        if (lane < DO) {
#pragma unroll
            for (int w4 = 0; w4 < 4; ++w4) tot += sDsum[w4][lane];
        }
        float p0 = (lane < DO) ? tot * fcw[lane*NCLS + 0] : 0.f;
        float p1 = (lane < DO) ? tot * fcw[lane*NCLS + 1] : 0.f;
#pragma unroll
        for (int d = 1; d <= 16; d <<= 1) {
            p0 += __shfl_xor(p0, d);
            p1 += __shfl_xor(p1, d);
        }
        if (lane == 0) {
            out[bb*NCLS + 0] = p0 + fcb[0];
            out[bb*NCLS + 1] = p1 + fcb[1];
        }
    }
}

// ---------------------------------------------------------------------------
extern "C" void kernel_launch(void* const* d_in, const int* in_sizes, int n_in,
                              void* d_out, int out_size, void* d_ws, size_t ws_size,
                              hipStream_t stream)
{
    const float* x     = (const float*)d_in[0];
    const float* y     = (const float*)d_in[1];
    const float* fr_w1 = (const float*)d_in[2];
    const float* fr_b1 = (const float*)d_in[3];
    const float* fr_w2 = (const float*)d_in[4];
    const float* fr_b2 = (const float*)d_in[5];
    const float* fr_w3 = (const float*)d_in[6];
    const float* fr_b3 = (const float*)d_in[7];
    const float* pv_w1 = (const float*)d_in[8];
    const float* pv_b1 = (const float*)d_in[9];
    const float* pv_w2 = (const float*)d_in[10];
    const float* pv_b2 = (const float*)d_in[11];
    const float* pv_w3 = (const float*)d_in[12];
    const float* pv_b3 = (const float*)d_in[13];
    const float* fo_w1 = (const float*)d_in[14];
    const float* fo_b1 = (const float*)d_in[15];
    const float* fo_w2 = (const float*)d_in[16];
    const float* fo_b2 = (const float*)d_in[17];
    const float* fo_w3 = (const float*)d_in[18];
    const float* fo_b3 = (const float*)d_in[19];
    const float* fc_w  = (const float*)d_in[20];
    const float* fc_b  = (const float*)d_in[21];
    float* out = (float*)d_out;

    char* wsb = (char*)d_ws;
    size_t off = 0;
    auto alloc = [&](size_t bytes) { char* p = wsb + off; off += (bytes + 255) & ~(size_t)255; return p; };

    _Float16* frW2p   = (_Float16*)alloc(4096*2);
    _Float16* frW3p16 = (_Float16*)alloc(2048*2);
    _Float16* pvW2p   = (_Float16*)alloc(4096*2);
    _Float16* pvW3p16 = (_Float16*)alloc(2048*2);
    _Float16* foW1p   = (_Float16*)alloc(4096*2);
    _Float16* foW2p16 = (_Float16*)alloc(4096*2);
    _Float16* foW3p16 = (_Float16*)alloc(2048*2);
    _Float16* frW1Ap  = (_Float16*)alloc(2048*2);
    _Float16* frW1Bp  = (_Float16*)alloc(2048*2);
    _Float16* pvW1Ap  = (_Float16*)alloc(2048*2);
    _Float16* xp      = (_Float16*)alloc((size_t)BATCH*NPART*32*2);

    int xblocks = (BATCH*NPART*4 + 255)/256;      // 480
    prep_kernel<<<16 + xblocks, 256, 0, stream>>>(
        x, fr_w1, fr_b1, pv_w1,
        fr_w2, fr_b2, fr_w3, fr_b3,
        pv_w2, pv_b2, pv_w3, pv_b3,
        fo_w1, fo_b1, fo_w2, fo_b2, fo_w3, fo_b3,
        frW2p, frW3p16, pvW2p, pvW3p16, foW1p, foW2p16, foW3p16,
        frW1Ap, frW1Bp, pvW1Ap, xp);

    fused_kernel<<<BATCH, 512, 0, stream>>>(
        y, pv_w1, pv_b1, fc_w, fc_b,
        (const half8*)frW2p, (const half4v*)frW3p16,
        (const half8*)pvW2p, (const half4v*)pvW3p16,
        (const half8*)foW1p, (const half4v*)foW2p16, (const half4v*)foW3p16,
        (const half8*)frW1Ap, (const half8*)frW1Bp,
        (const half8*)pvW1Ap, xp,
        out);
}